// Round 10
// baseline (925.661 us; speedup 1.0000x reference)
//
#include <hip/hip_runtime.h>
#include <math.h>

#define NROWS 16384
#define DIN   384
#define DIM   512
#define KSEL  6
#define NSPLIT 4
#define COLS_PER_SPLIT (NROWS / NSPLIT)   // 4096
#define ATT_SCALE 0.044194173824159216f   // 512^-0.5

typedef unsigned short u16;
typedef __attribute__((ext_vector_type(8))) short bf16x8;
typedef __attribute__((ext_vector_type(16))) float f32x16;

static __device__ __forceinline__ float lrelu_f(float v) {
  return v > 0.f ? v : 0.01f * v;
}

static __device__ __forceinline__ u16 f2bf(float f) {  // RNE f32->bf16
  unsigned u = __float_as_uint(f);
  unsigned r = (u + 0x7FFFu + ((u >> 16) & 1u)) >> 16;
  return (u16)r;
}

static __device__ __forceinline__ void sbar() {
  asm volatile("" ::: "memory");
  __builtin_amdgcn_s_barrier();
  asm volatile("" ::: "memory");
}

// ---------------------------------------------------------------------------
// prep: all f32->bf16 conversions in ONE launch (input + 6 transposed weights)
// ---------------------------------------------------------------------------
static __device__ __forceinline__ void wconv_body(const float* W, u16* Wt,
                                                  int K, int N, int t) {
  if (t >= K * N) return;
  int k = t / N, n = t - k * N;
  Wt[(size_t)n * K + k] = f2bf(W[t]);
}

__global__ __launch_bounds__(256)
void prep(const float* __restrict__ X, u16* __restrict__ Xb,
          const float* __restrict__ fc1_w, u16* __restrict__ fc1t,
          const float* __restrict__ wh_w, u16* __restrict__ wht,
          const float* __restrict__ wt_w, u16* __restrict__ wtt,
          const float* __restrict__ lin1_w, u16* __restrict__ lin1t,
          const float* __restrict__ lin2_w, u16* __restrict__ lin2t,
          const float* __restrict__ att1_w, u16* __restrict__ att1t) {
  const int b = blockIdx.x, tid = threadIdx.x;
  if (b < 3072) {
    int i = b * 256 + tid;                     // 8-elem chunk of x
    const float4* p = (const float4*)X + (size_t)i * 2;
    float4 a = p[0], c = p[1];
    uint4 o;
    o.x = f2bf(a.x) | ((unsigned)f2bf(a.y) << 16);
    o.y = f2bf(a.z) | ((unsigned)f2bf(a.w) << 16);
    o.z = f2bf(c.x) | ((unsigned)f2bf(c.y) << 16);
    o.w = f2bf(c.z) | ((unsigned)f2bf(c.w) << 16);
    ((uint4*)Xb)[i] = o;
  } else if (b < 3840) {
    wconv_body(fc1_w, fc1t, 384, 512, (b - 3072) * 256 + tid);
  } else if (b < 4864) {
    wconv_body(wh_w, wht, 512, 512, (b - 3840) * 256 + tid);
  } else if (b < 5888) {
    wconv_body(wt_w, wtt, 512, 512, (b - 4864) * 256 + tid);
  } else if (b < 6912) {
    wconv_body(lin1_w, lin1t, 512, 512, (b - 5888) * 256 + tid);
  } else if (b < 7936) {
    wconv_body(lin2_w, lin2t, 512, 512, (b - 6912) * 256 + tid);
  } else {
    wconv_body(att1_w, att1t, 512, 256, (b - 7936) * 256 + tid);
  }
}

__global__ __launch_bounds__(256)
void colsum_partial(const float* __restrict__ H, float* __restrict__ part) {
  int col = blockIdx.x * 64 + (threadIdx.x & 63);
  int sub = threadIdx.x >> 6;
  int rEnd = blockIdx.y * 512 + 512;
  float s = 0.f;
  for (int r = blockIdx.y * 512 + sub; r < rEnd; r += 4)
    s += H[(size_t)r * DIM + col];
  __shared__ float sh[4][64];
  sh[sub][threadIdx.x & 63] = s;
  __syncthreads();
  if (threadIdx.x < 64) {
    float tot = sh[0][threadIdx.x] + sh[1][threadIdx.x] +
                sh[2][threadIdx.x] + sh[3][threadIdx.x];
    part[(size_t)blockIdx.y * DIM + col] = tot;
  }
}

__global__ void finalize_mean(const float* __restrict__ part,
                              float* __restrict__ mean) {
  int c = threadIdx.x;
  float s = 0.f;
  for (int j = 0; j < 32; j++) s += part[j * DIM + c];
  mean[c] = s * (1.0f / NROWS);
}

// h = (h0 + mean)*0.5, bf16 output only
__global__ __launch_bounds__(256)
void h_fix_bf(const float* __restrict__ H0, const float* __restrict__ mean,
              u16* __restrict__ Hb) {
  int idx = blockIdx.x * 256 + threadIdx.x;         // 8-elem chunk
  int c = (idx * 8) & (DIM - 1);
  const float4* p = (const float4*)H0 + (size_t)idx * 2;
  float4 a = p[0], b = p[1];
  float4 m0 = *(const float4*)(mean + c);
  float4 m1 = *(const float4*)(mean + c + 4);
  a.x = (a.x + m0.x) * 0.5f; a.y = (a.y + m0.y) * 0.5f;
  a.z = (a.z + m0.z) * 0.5f; a.w = (a.w + m0.w) * 0.5f;
  b.x = (b.x + m1.x) * 0.5f; b.y = (b.y + m1.y) * 0.5f;
  b.z = (b.z + m1.z) * 0.5f; b.w = (b.w + m1.w) * 0.5f;
  uint4 o;
  o.x = f2bf(a.x) | ((unsigned)f2bf(a.y) << 16);
  o.y = f2bf(a.z) | ((unsigned)f2bf(a.w) << 16);
  o.z = f2bf(b.x) | ((unsigned)f2bf(b.y) << 16);
  o.w = f2bf(b.z) | ((unsigned)f2bf(b.w) << 16);
  ((uint4*)Hb)[idx] = o;
}

// ---------------------------------------------------------------------------
// bf16 MFMA GEMM (unchanged): C = act(A@Wt^T + bias), opt +=, opt bf16 store.
// ---------------------------------------------------------------------------
template<int ACT, int ACCUM, int STOREBF>
__global__ __launch_bounds__(256, 2)
void gemm_bf16(const u16* __restrict__ A, const u16* __restrict__ Wt,
               const float* __restrict__ bias, float* __restrict__ C,
               u16* __restrict__ Cb, float bscale, int K, int N) {
  __shared__ char lds[65536];   // A dbuf [0,32K), W dbuf [32K,64K)
  const int tid = threadIdx.x;
  const int w = tid >> 6, l = tid & 63;
  const int l31 = l & 31, lh = l >> 5, lh16 = lh << 4;
  const int qg = w & 1, ng = w >> 1;
  const int swz = (l31 & 7) << 4;
  const int rowBase = blockIdx.y * 128;
  const int colBase = blockIdx.x * 128;
  const int nsteps = K >> 6;

  f32x16 z;
  #pragma unroll
  for (int i = 0; i < 16; i++) z[i] = 0.f;
  f32x16 acc00 = z, acc01 = z, acc10 = z, acc11 = z;

#define GSTAGE(buf_, kc_) do { \
    const int r_ = tid >> 3, j_ = tid & 7; \
    const int js_ = ((j_ ^ (r_ & 7)) << 3); \
    const u16* as_ = A + (size_t)rowBase * K + (kc_); \
    const u16* ws_ = Wt + (size_t)colBase * K + (kc_); \
    char* ab_ = lds + (buf_) * 16384; \
    char* wb_ = lds + 32768 + (buf_) * 16384; \
    _Pragma("unroll") \
    for (int p_ = 0; p_ < 4; ++p_) { \
      __builtin_amdgcn_global_load_lds( \
        (const __attribute__((address_space(1))) void*)(as_ + (size_t)(r_ + 32 * p_) * K + js_), \
        (__attribute__((address_space(3))) void*)(ab_ + w * 1024 + p_ * 4096), 16, 0, 0); \
      __builtin_amdgcn_global_load_lds( \
        (const __attribute__((address_space(1))) void*)(ws_ + (size_t)(r_ + 32 * p_) * K + js_), \
        (__attribute__((address_space(3))) void*)(wb_ + w * 1024 + p_ * 4096), 16, 0, 0); \
    } \
  } while (0)

  GSTAGE(0, 0);
  asm volatile("s_waitcnt vmcnt(0)" ::: "memory");
  sbar();
  #pragma unroll 1
  for (int s = 0; s < nsteps; ++s) {
    const int cur = s & 1;
    if (s + 1 < nsteps) GSTAGE(cur ^ 1, (s + 1) * 64);
    __builtin_amdgcn_sched_barrier(0);
    const char* ab = lds + cur * 16384;
    const char* wb = lds + 32768 + cur * 16384;
    __builtin_amdgcn_s_setprio(1);
    #pragma unroll
    for (int s4 = 0; s4 < 4; ++s4) {
      const int off = (s4 * 32 + lh16) ^ swz;
      bf16x8 am0 = *(const bf16x8*)(ab + (qg * 64 + l31) * 128 + off);
      bf16x8 am1 = *(const bf16x8*)(ab + (qg * 64 + 32 + l31) * 128 + off);
      bf16x8 wn0 = *(const bf16x8*)(wb + (ng * 64 + l31) * 128 + off);
      bf16x8 wn1 = *(const bf16x8*)(wb + (ng * 64 + 32 + l31) * 128 + off);
      acc00 = __builtin_amdgcn_mfma_f32_32x32x16_bf16(wn0, am0, acc00, 0, 0, 0);
      acc01 = __builtin_amdgcn_mfma_f32_32x32x16_bf16(wn1, am0, acc01, 0, 0, 0);
      acc10 = __builtin_amdgcn_mfma_f32_32x32x16_bf16(wn0, am1, acc10, 0, 0, 0);
      acc11 = __builtin_amdgcn_mfma_f32_32x32x16_bf16(wn1, am1, acc11, 0, 0, 0);
    }
    __builtin_amdgcn_s_setprio(0);
    asm volatile("s_waitcnt vmcnt(0)" ::: "memory");
    sbar();
  }
#undef GSTAGE

  // epilogue: spill to LDS (XOR-swizzled cols), then coalesced store
  float* Ls = (float*)lds;
  {
    const int m0 = qg * 64 + l31;
    const int k0 = (m0 & 7) << 2;
    #pragma unroll
    for (int r = 0; r < 16; ++r) {
      const int nd = ng * 64 + (r & 3) + 8 * (r >> 2) + 4 * lh;
      Ls[m0 * 128 + (nd ^ k0)] = acc00[r];
      Ls[m0 * 128 + ((nd + 32) ^ k0)] = acc01[r];
      Ls[(m0 + 32) * 128 + (nd ^ k0)] = acc10[r];
      Ls[(m0 + 32) * 128 + ((nd + 32) ^ k0)] = acc11[r];
    }
  }
  sbar();
  #pragma unroll
  for (int p = 0; p < 16; ++p) {
    int idx = tid + 256 * p;
    int m = idx >> 5, c4 = (idx & 31) << 2;
    float4 v = *(const float4*)&Ls[m * 128 + (c4 ^ ((m & 7) << 2))];
    int col = colBase + c4;
    float4 bv = *(const float4*)&bias[col];
    v.x += bv.x; v.y += bv.y; v.z += bv.z; v.w += bv.w;
    if (ACT) {
      v.x = lrelu_f(v.x); v.y = lrelu_f(v.y);
      v.z = lrelu_f(v.z); v.w = lrelu_f(v.w);
    }
    size_t o = (size_t)(rowBase + m) * N + col;
    if (ACCUM) {
      float4 c0 = *(const float4*)&C[o];
      v.x += c0.x; v.y += c0.y; v.z += c0.z; v.w += c0.w;
    }
    *(float4*)&C[o] = v;
    if (STOREBF) {
      ushort4 q;
      q.x = f2bf(v.x * bscale); q.y = f2bf(v.y * bscale);
      q.z = f2bf(v.z * bscale); q.w = f2bf(v.w * bscale);
      *(ushort4*)&Cb[o] = q;
    }
  }
}

// ---------------------------------------------------------------------------
// MFMA attn-logit + per-row top-6 — shared-B, 2-buffer stage-first pipeline,
// HIGH OCCUPANCY: 1024 blocks x 256 thr (4 waves), 3 blocks/CU (32 KB LDS,
// launch_bounds(256,3) -> ~12 waves/CU). Decode: xcd=bid&7, rem=bid>>3,
// rowTileL=rem&15, sc=rem>>4 (split=sc&3, ch=sc>>2).
// rowBase=(xcd*16+rowTileL)*128 (per-XCD A = 2 MB, L2-resident, R5-verified);
// cols = split*4096 + ch*2048 .. +2048 (32 ct x 4 kc = 128 phases).
// Per wave: 32 q-rows; A (query) full K=512 in 128 regs (loaded once).
// Phase p: {sbar; STAGE(p+1 -> buf (p+1)&1); 16 ds_read + 16 MFMA (setprio);
// [T6 at kc==3]; vmcnt(0)}. Stage-first gives loads the whole compute phase.
// Swizzle j^=(n&15) involution both sides (R9-verified, 0 bank conflicts).
// Output: 8 partial lists (split*2+ch) merged downstream.
// ---------------------------------------------------------------------------
#define T6(tv, tix, vv, cc) do { float v_ = (vv); \
  if (v_ > tv[5]) { tv[5] = v_; tix[5] = (cc); \
    if (tv[5] > tv[4]) { float t=tv[4];tv[4]=tv[5];tv[5]=t; int q=tix[4];tix[4]=tix[5];tix[5]=q; } \
    if (tv[4] > tv[3]) { float t=tv[3];tv[3]=tv[4];tv[4]=t; int q=tix[3];tix[3]=tix[4];tix[4]=q; } \
    if (tv[3] > tv[2]) { float t=tv[2];tv[2]=tv[3];tv[3]=t; int q=tix[2];tix[2]=tix[3];tix[3]=q; } \
    if (tv[2] > tv[1]) { float t=tv[1];tv[1]=tv[2];tv[2]=t; int q=tix[1];tix[1]=tix[2];tix[2]=q; } \
    if (tv[1] > tv[0]) { float t=tv[0];tv[0]=tv[1];tv[1]=t; int q=tix[0];tix[0]=tix[1];tix[1]=q; } \
  } } while (0)

__global__ __launch_bounds__(256, 3)
void attn_topk_mfma(const u16* __restrict__ EHb, const u16* __restrict__ ETb,
                    float* __restrict__ TWp, int* __restrict__ TIp) {
  __shared__ char lds[32768];            // 2 shared B buffers x 16 KB
  const int tid = threadIdx.x;
  const int w = tid >> 6, l = tid & 63;
  const int l31 = l & 31, lh = l >> 5;

  const int bid = blockIdx.x;
  const int xcd = bid & 7;
  const int rem = bid >> 3;
  const int rowTileL = rem & 15;
  const int sc = rem >> 4;               // 0..7
  const int split = sc & 3;
  const int ch = sc >> 2;
  const int rowBase = (xcd * 16 + rowTileL) * 128;
  const int colBase0 = split * COLS_PER_SPLIT + ch * 2048;
  const int qrow = rowBase + w * 32 + l31;     // this lane's query row

  // ---- A (query) fragments in registers: full K=512, 32 x bf16x8 ----
  bf16x8 areg[32];
  {
    const u16* ap = EHb + (size_t)qrow * DIM + lh * 8;
    #pragma unroll
    for (int ks = 0; ks < 32; ++ks)
      areg[ks] = *(const bf16x8*)(ap + ks * 16);
  }

  f32x16 z;
  #pragma unroll
  for (int i = 0; i < 16; i++) z[i] = 0.f;
  f32x16 acc0 = z, acc1 = z;

  float tv[KSEL]; int tix[KSEL];
  #pragma unroll
  for (int k = 0; k < KSEL; k++) { tv[k] = -INFINITY; tix[k] = 0x7fffffff; }

  // Stage one 64n x 128k tile (16 KB): 4 gload_lds per thread.
  // chunk c in [0,1024): LDS granule c (16B) holds logical
  // (n = c>>4, j = (c&15) ^ (n&15)) -> source pre-swizzled (rule #21).
#define STAGE(bufi_, ph_) do { \
    const int ct_ = (ph_) >> 2, kc_ = (ph_) & 3; \
    char* db_ = lds + (bufi_) * 16384; \
    const u16* bs_ = ETb + (size_t)(colBase0 + ct_ * 64) * DIM + kc_ * 128; \
    _Pragma("unroll") \
    for (int p_ = 0; p_ < 4; ++p_) { \
      const int c_ = (w * 4 + p_) * 64 + l; \
      const int rn_ = c_ >> 4; \
      const int js_ = ((c_ & 15) ^ (rn_ & 15)) << 3; \
      __builtin_amdgcn_global_load_lds( \
        (const __attribute__((address_space(1))) void*)(bs_ + (size_t)rn_ * DIM + js_), \
        (__attribute__((address_space(3))) void*)(db_ + (w * 4 + p_) * 1024), 16, 0, 0); \
    } \
  } while (0)

  STAGE(0, 0);
  asm volatile("s_waitcnt vmcnt(0)" ::: "memory");

  #pragma unroll 1
  for (int ct = 0; ct < 32; ++ct) {
    #pragma unroll
    for (int kc = 0; kc < 4; ++kc) {
      const int p = ct * 4 + kc;
      sbar();                              // stage(p) landed; p-1 reads done
      if (p + 1 < 128) STAGE((p + 1) & 1, p + 1);
      __builtin_amdgcn_sched_barrier(0);
      const char* db = lds + (p & 1) * 16384;
      __builtin_amdgcn_s_setprio(1);
      #pragma unroll
      for (int s = 0; s < 8; ++s) {
        const int j0 = ((s * 2 + lh) ^ (l31 & 15)) * 16;
        bf16x8 bn0 = *(const bf16x8*)(db + l31 * 256 + j0);
        const int r1 = 32 + l31;
        const int j1 = ((s * 2 + lh) ^ (r1 & 15)) * 16;
        bf16x8 bn1 = *(const bf16x8*)(db + r1 * 256 + j1);
        acc0 = __builtin_amdgcn_mfma_f32_32x32x16_bf16(bn0, areg[kc * 8 + s], acc0, 0, 0, 0);
        acc1 = __builtin_amdgcn_mfma_f32_32x32x16_bf16(bn1, areg[kc * 8 + s], acc1, 0, 0, 0);
      }
      __builtin_amdgcn_s_setprio(0);
      if (kc == 3) {                       // end of K for this 64-col tile
        const int cb = colBase0 + ct * 64 + 4 * lh;
        #pragma unroll
        for (int r = 0; r < 16; ++r) {
          const int nd = cb + (r & 3) + 8 * (r >> 2);
          T6(tv, tix, acc0[r], nd);
          T6(tv, tix, acc1[r], nd + 32);
        }
        acc0 = z; acc1 = z;
      }
      __builtin_amdgcn_sched_barrier(0);
      asm volatile("s_waitcnt vmcnt(0)" ::: "memory");  // stage(p+1) landed
    }
  }
#undef STAGE

  // merge the two lh-half lists for this q-row (partner lane = l ^ 32)
  {
    float pv[KSEL]; int pi[KSEL];
    #pragma unroll
    for (int k = 0; k < KSEL; k++) {
      pv[k] = __shfl_xor(tv[k], 32);
      pi[k] = __shfl_xor(tix[k], 32);
    }
    #pragma unroll
    for (int k = 0; k < KSEL; k++) {
      float cv = pv[k]; int ci = pi[k];
      if ((cv > tv[5]) || (cv == tv[5] && ci < tix[5])) {
        tv[5] = cv; tix[5] = ci;
        if ((tv[5] > tv[4]) || (tv[5] == tv[4] && tix[5] < tix[4])) {
          float t = tv[4]; tv[4] = tv[5]; tv[5] = t;
          int q = tix[4]; tix[4] = tix[5]; tix[5] = q; }
        if ((tv[4] > tv[3]) || (tv[4] == tv[3] && tix[4] < tix[3])) {
          float t = tv[3]; tv[3] = tv[4]; tv[4] = t;
          int q = tix[3]; tix[3] = tix[4]; tix[4] = q; }
        if ((tv[3] > tv[2]) || (tv[3] == tv[2] && tix[3] < tix[2])) {
          float t = tv[2]; tv[2] = tv[3]; tv[3] = t;
          int q = tix[2]; tix[2] = tix[3]; tix[3] = q; }
        if ((tv[2] > tv[1]) || (tv[2] == tv[1] && tix[2] < tix[1])) {
          float t = tv[1]; tv[1] = tv[2]; tv[2] = t;
          int q = tix[1]; tix[1] = tix[2]; tix[2] = q; }
        if ((tv[1] > tv[0]) || (tv[1] == tv[0] && tix[1] < tix[0])) {
          float t = tv[0]; tv[0] = tv[1]; tv[1] = t;
          int q = tix[0]; tix[0] = tix[1]; tix[1] = q; }
      }
    }
  }
  if (lh == 0) {
    size_t o = ((size_t)(split * 2 + ch) * NROWS + qrow) * KSEL;
    #pragma unroll
    for (int k = 0; k < KSEL; k++) { TWp[o + k] = tv[k]; TIp[o + k] = tix[k]; }
  }
}

// ---------------------------------------------------------------------------
// Neighbor aggregation + inline 8-slot top-6 merge. One wave per row.
// ---------------------------------------------------------------------------
__global__ __launch_bounds__(256)
void neighbor_kernel(const float* __restrict__ EH, const float* __restrict__ ET,
                     const float* __restrict__ TWp, const int* __restrict__ TIp,
                     u16* __restrict__ SINb, u16* __restrict__ BINb) {
  const int lane = threadIdx.x & 63;
  const int row = blockIdx.x * 4 + (threadIdx.x >> 6);
  const float* eh = EH + (size_t)row * DIM;
  float ehv[8];
  #pragma unroll
  for (int u = 0; u < 8; u++) ehv[u] = eh[u * 64 + lane];

  // inline merge of the 8 partial top-6 lists (value desc, idx asc)
  float tw[KSEL]; int ti[KSEL];
  #pragma unroll
  for (int k = 0; k < KSEL; k++) { tw[k] = -INFINITY; ti[k] = 0x7fffffff; }
  #pragma unroll
  for (int s = 0; s < 8; s++) {
    size_t o = ((size_t)s * NROWS + row) * KSEL;
    #pragma unroll
    for (int k = 0; k < KSEL; k++) {
      float cv = TWp[o + k]; int ci = TIp[o + k];
      if ((cv > tw[5]) || (cv == tw[5] && ci < ti[5])) {
        tw[5] = cv; ti[5] = ci;
        if ((tw[5] > tw[4]) || (tw[5] == tw[4] && ti[5] < ti[4])) {
          float t = tw[4]; tw[4] = tw[5]; tw[5] = t;
          int q = ti[4]; ti[4] = ti[5]; ti[5] = q; }
        if ((tw[4] > tw[3]) || (tw[4] == tw[3] && ti[4] < ti[3])) {
          float t = tw[3]; tw[3] = tw[4]; tw[4] = t;
          int q = ti[3]; ti[3] = ti[4]; ti[4] = q; }
        if ((tw[3] > tw[2]) || (tw[3] == tw[2] && ti[3] < ti[2])) {
          float t = tw[2]; tw[2] = tw[3]; tw[3] = t;
          int q = ti[2]; ti[2] = ti[3]; ti[3] = q; }
        if ((tw[2] > tw[1]) || (tw[2] == tw[1] && ti[2] < ti[1])) {
          float t = tw[1]; tw[1] = tw[2]; tw[2] = t;
          int q = ti[1]; ti[1] = ti[2]; ti[2] = q; }
        if ((tw[1] > tw[0]) || (tw[1] == tw[0] && ti[1] < ti[0])) {
          float t = tw[0]; tw[0] = tw[1]; tw[1] = t;
          int q = ti[0]; ti[0] = ti[1]; ti[1] = q; }
      }
    }
  }

  float m = tw[0];
  #pragma unroll
  for (int k = 1; k < KSEL; k++) m = fmaxf(m, tw[k]);
  float p[KSEL], ps = 0.f;
  #pragma unroll
  for (int k = 0; k < KSEL; k++) { p[k] = expf(tw[k] - m); ps += p[k]; }
  float inv = 1.f / ps;
  #pragma unroll
  for (int k = 0; k < KSEL; k++) p[k] *= inv;

  float nb[KSEL][8];
  float kaw[KSEL];
  #pragma unroll
  for (int k = 0; k < KSEL; k++) {
    const float* et = ET + (size_t)ti[k] * DIM;
    float snb = 0.f, sg = 0.f;
    #pragma unroll
    for (int u = 0; u < 8; u++) {
      float nbv = et[u * 64 + lane];
      nb[k][u] = nbv;
      float ehr = p[k] * nbv + (1.f - p[k]) * ehv[u];
      float g = tanhf(ehv[u] + ehr);
      snb += nbv; sg += g;
    }
    #pragma unroll
    for (int off = 32; off > 0; off >>= 1) {
      snb += __shfl_xor(snb, off);
      sg  += __shfl_xor(sg, off);
    }
    kaw[k] = snb * sg;
  }
  float km = kaw[0];
  #pragma unroll
  for (int k = 1; k < KSEL; k++) km = fmaxf(km, kaw[k]);
  float kp[KSEL], ks = 0.f;
  #pragma unroll
  for (int k = 0; k < KSEL; k++) { kp[k] = expf(kaw[k] - km); ks += kp[k]; }
  float kinv = 1.f / ks;
  #pragma unroll
  for (int k = 0; k < KSEL; k++) kp[k] *= kinv;

  #pragma unroll
  for (int u = 0; u < 8; u++) {
    float enh = 0.f;
    #pragma unroll
    for (int k = 0; k < KSEL; k++) enh += kp[k] * nb[k][u];
    size_t o = (size_t)row * DIM + u * 64 + lane;
    SINb[o] = f2bf(ehv[u] + enh);
    BINb[o] = f2bf(ehv[u] * enh);
  }
}

__global__ __launch_bounds__(256)
void att2_kernel(const float* __restrict__ HID, const float* __restrict__ w2,
                 const float* __restrict__ b2, float* __restrict__ ASC) {
  const int lane = threadIdx.x & 63;
  const int row = blockIdx.x * 4 + (threadIdx.x >> 6);
  float4 hv = ((const float4*)(HID + (size_t)row * 256))[lane];
  float4 wv = ((const float4*)w2)[lane];
  float s = hv.x * wv.x + hv.y * wv.y + hv.z * wv.z + hv.w * wv.w;
  #pragma unroll
  for (int off = 32; off > 0; off >>= 1) s += __shfl_xor(s, off);
  if (lane == 0) ASC[row] = s + b2[0];
}

__global__ __launch_bounds__(1024)
void areduce(const float* __restrict__ ASC, float* __restrict__ stats) {
  __shared__ float sm[1024];
  int t = threadIdx.x;
  float m = -INFINITY;
  for (int i = t; i < NROWS; i += 1024) m = fmaxf(m, ASC[i]);
  sm[t] = m; __syncthreads();
  for (int s = 512; s > 0; s >>= 1) {
    if (t < s) sm[t] = fmaxf(sm[t], sm[t + s]);
    __syncthreads();
  }
  float mx = sm[0]; __syncthreads();
  float sum = 0.f;
  for (int i = t; i < NROWS; i += 1024) sum += expf(ASC[i] - mx);
  sm[t] = sum; __syncthreads();
  for (int s = 512; s > 0; s >>= 1) {
    if (t < s) sm[t] += sm[t + s];
    __syncthreads();
  }
  if (t == 0) { stats[0] = mx; stats[1] = sm[0]; }
}

__global__ __launch_bounds__(256)
void pooled_partial(const float* __restrict__ EMB, const float* __restrict__ ASC,
                    const float* __restrict__ stats, float* __restrict__ part) {
  int col = blockIdx.x * 64 + (threadIdx.x & 63);
  int sub = threadIdx.x >> 6;
  float mx = stats[0];
  int rEnd = blockIdx.y * 512 + 512;
  float s = 0.f;
  for (int r = blockIdx.y * 512 + sub; r < rEnd; r += 4)
    s += expf(ASC[r] - mx) * EMB[(size_t)r * DIM + col];
  __shared__ float sh[4][64];
  sh[sub][threadIdx.x & 63] = s;
  __syncthreads();
  if (threadIdx.x < 64) {
    float tot = sh[0][threadIdx.x] + sh[1][threadIdx.x] +
                sh[2][threadIdx.x] + sh[3][threadIdx.x];
    part[(size_t)blockIdx.y * DIM + col] = tot;
  }
}

__global__ __launch_bounds__(512)
void final_kernel(const float* __restrict__ part, const float* __restrict__ stats,
                  const float* __restrict__ ln_g, const float* __restrict__ ln_b,
                  const float* __restrict__ fc_w, const float* __restrict__ fc_b,
                  float* __restrict__ out) {
  __shared__ float sh[512];
  int t = threadIdx.x;
  float s = 0.f;
  for (int j = 0; j < 32; j++) s += part[j * DIM + t];
  float pooled = s / stats[1];
  sh[t] = pooled; __syncthreads();
  for (int off = 256; off > 0; off >>= 1) {
    if (t < off) sh[t] += sh[t + off];
    __syncthreads();
  }
  float mu = sh[0] * (1.f / DIM); __syncthreads();
  float dv = pooled - mu;
  sh[t] = dv * dv; __syncthreads();
  for (int off = 256; off > 0; off >>= 1) {
    if (t < off) sh[t] += sh[t + off];
    __syncthreads();
  }
  float var = sh[0] * (1.f / DIM); __syncthreads();
  float normed = dv * rsqrtf(var + 1e-5f) * ln_g[t] + ln_b[t];
  sh[t] = normed * fc_w[t * 2 + 0]; __syncthreads();
  for (int off = 256; off > 0; off >>= 1) {
    if (t < off) sh[t] += sh[t + off];
    __syncthreads();
  }
  float l0 = sh[0] + fc_b[0]; __syncthreads();
  sh[t] = normed * fc_w[t * 2 + 1]; __syncthreads();
  for (int off = 256; off > 0; off >>= 1) {
    if (t < off) sh[t] += sh[t + off];
    __syncthreads();
  }
  float l1 = sh[0] + fc_b[1];
  if (t == 0) {
    float mm = fmaxf(l0, l1);
    float e0 = expf(l0 - mm), e1 = expf(l1 - mm);
    float si = 1.f / (e0 + e1);
    out[0] = l0; out[1] = l1; out[2] = e0 * si; out[3] = e1 * si;
  }
}

// ---------------------------------------------------------------------------
extern "C" void kernel_launch(void* const* d_in, const int* in_sizes, int n_in,
                              void* d_out, int out_size, void* d_ws, size_t ws_size,
                              hipStream_t stream) {
  (void)in_sizes; (void)n_in; (void)out_size; (void)ws_size;
  const float* x      = (const float*)d_in[0];
  const float* fc1_w  = (const float*)d_in[1];
  const float* fc1_b  = (const float*)d_in[2];
  const float* wh_w   = (const float*)d_in[3];
  const float* wh_b   = (const float*)d_in[4];
  const float* wt_w   = (const float*)d_in[5];
  const float* wt_b   = (const float*)d_in[6];
  const float* lin1_w = (const float*)d_in[7];
  const float* lin1_b = (const float*)d_in[8];
  const float* lin2_w = (const float*)d_in[9];
  const float* lin2_b = (const float*)d_in[10];
  const float* att1_w = (const float*)d_in[11];
  const float* att1_b = (const float*)d_in[12];
  const float* att2_w = (const float*)d_in[13];
  const float* att2_b = (const float*)d_in[14];
  const float* ln_g   = (const float*)d_in[15];
  const float* ln_b   = (const float*)d_in[16];
  const float* fc_w   = (const float*)d_in[17];
  const float* fc_b   = (const float*)d_in[18];
  float* out = (float*)d_out;

  char* ws = (char*)d_ws;
  float* B0   = (float*)(ws);                       // h0 -> TWp/TIp -> HID
  float* B1   = (float*)(ws + 33554432);            // [xb] -> e_h
  float* B2   = (float*)(ws + 67108864);            // e_t -> emb
  float* part = (float*)(ws + 100663296 + 3145728 + 786432);
  float* mean = (float*)(ws + 100663296 + 3145728 + 786432 + 65536);
  float* ascr = (float*)(ws + 100663296 + 3145728 + 786432 + 65536 + 2048);
  float* stats= (float*)(ws + 100663296 + 3145728 + 786432 + 65536 + 2048 + 65536);
  u16*   hb   = (u16*)(ws + 104732672);             // -> embb
  u16*   EHb  = (u16*)(ws + 104732672 + 16777216);  // -> sinb
  u16*   ETb  = (u16*)(ws + 104732672 + 33554432);  // -> binb
  u16*   WT   = (u16*)(ws + 104732672 + 50331648);  // transposed bf16 weights
  u16* fc1t = WT;
  u16* wht  = fc1t + 196608;
  u16* wtt  = wht + 262144;
  u16* lin1t= wtt + 262144;
  u16* lin2t= lin1t + 262144;
  u16* att1t= lin2t + 262144;
  u16* xb   = (u16*)B1;      // temp in B1 region, dead before e_h written
  u16* sinb = EHb;           // reuse after attn
  u16* binb = ETb;
  u16* embb = hb;
  // TWp/TIp live in the dead h0 (B0) region between attn and neighbor;
  // 8 slots x NROWS x 6: 3 MB each. HID overwrites B0 only after neighbor.
  float* TWp = B0;
  int*   TIp = (int*)(ws + 8 * (size_t)NROWS * KSEL * 4);

  // 0. all bf16 conversions in one launch
  prep<<<8448, 256, 0, stream>>>(x, xb, fc1_w, fc1t, wh_w, wht, wt_w, wtt,
                                 lin1_w, lin1t, lin2_w, lin2t, att1_w, att1t);
  // 1. h0 = lrelu(x @ fc1_w + b)
  gemm_bf16<1,0,0><<<dim3(4,128), 256, 0, stream>>>(xb, fc1t, fc1_b, B0, nullptr, 1.f, 384, 512);
  // 2-4. column mean; hb = bf16((h0+mean)*0.5)
  colsum_partial<<<dim3(8,32), 256, 0, stream>>>(B0, part);
  finalize_mean<<<1, 512, 0, stream>>>(part, mean);
  h_fix_bf<<<4096, 256, 0, stream>>>(B0, mean, hb);
  // 5-6. e_h (f32 + bf16*SCALE), e_t (f32 + bf16)
  gemm_bf16<0,0,1><<<dim3(4,128), 256, 0, stream>>>(hb, wht, wh_b, B1, EHb, ATT_SCALE, 512, 512);
  gemm_bf16<0,0,1><<<dim3(4,128), 256, 0, stream>>>(hb, wtt, wt_b, B2, ETb, 1.f, 512, 512);
  // 7. fused MFMA attn-logit + top-6 (1024 blocks, 2-buffer stage-first)
  attn_topk_mfma<<<1024, 256, 0, stream>>>(EHb, ETb, TWp, TIp);
  // 8. neighbor aggregation (inline 8-slot merge) -> bf16 s_in / b_in
  neighbor_kernel<<<4096, 256, 0, stream>>>(B1, B2, TWp, TIp, sinb, binb);
  // 9-10. emb = lrelu(s_in@lin1+b) + lrelu(b_in@lin2+b)  (f32 in B2 + bf16)
  gemm_bf16<1,0,0><<<dim3(4,128), 256, 0, stream>>>(sinb, lin1t, lin1_b, B2, nullptr, 1.f, 512, 512);
  gemm_bf16<1,1,1><<<dim3(4,128), 256, 0, stream>>>(binb, lin2t, lin2_b, B2, embb, 1.f, 512, 512);
  // 11. hidden = lrelu(emb@att1+b) -> B0 f32 (TWp dead now)
  gemm_bf16<1,0,0><<<dim3(2,128), 256, 0, stream>>>(embb, att1t, att1_b, B0, nullptr, 1.f, 512, 256);
  // 12-15. readout
  att2_kernel<<<4096, 256, 0, stream>>>(B0, att2_w, att2_b, ascr);
  areduce<<<1, 1024, 0, stream>>>(ascr, stats);
  pooled_partial<<<dim3(8,32), 256, 0, stream>>>(B2, ascr, stats, part);
  final_kernel<<<1, 512, 0, stream>>>(part, stats, ln_g, ln_b, fc_w, fc_b, out);
}

// Round 11
// 587.888 us; speedup vs baseline: 1.5746x; 1.5746x over previous
//
#include <hip/hip_runtime.h>
#include <math.h>

#define NROWS 16384
#define DIN   384
#define DIM   512
#define KSEL  6
#define NSPLIT 4
#define COLS_PER_SPLIT (NROWS / NSPLIT)   // 4096
#define ATT_SCALE 0.044194173824159216f   // 512^-0.5

typedef unsigned short u16;
typedef __attribute__((ext_vector_type(8))) short bf16x8;
typedef __attribute__((ext_vector_type(16))) float f32x16;

static __device__ __forceinline__ float lrelu_f(float v) {
  return v > 0.f ? v : 0.01f * v;
}

static __device__ __forceinline__ u16 f2bf(float f) {  // RNE f32->bf16
  unsigned u = __float_as_uint(f);
  unsigned r = (u + 0x7FFFu + ((u >> 16) & 1u)) >> 16;
  return (u16)r;
}

static __device__ __forceinline__ void sbar() {
  asm volatile("" ::: "memory");
  __builtin_amdgcn_s_barrier();
  asm volatile("" ::: "memory");
}

// ---------------------------------------------------------------------------
// prep: all f32->bf16 conversions in ONE launch (input + 6 transposed weights)
// ---------------------------------------------------------------------------
static __device__ __forceinline__ void wconv_body(const float* W, u16* Wt,
                                                  int K, int N, int t) {
  if (t >= K * N) return;
  int k = t / N, n = t - k * N;
  Wt[(size_t)n * K + k] = f2bf(W[t]);
}

__global__ __launch_bounds__(256)
void prep(const float* __restrict__ X, u16* __restrict__ Xb,
          const float* __restrict__ fc1_w, u16* __restrict__ fc1t,
          const float* __restrict__ wh_w, u16* __restrict__ wht,
          const float* __restrict__ wt_w, u16* __restrict__ wtt,
          const float* __restrict__ lin1_w, u16* __restrict__ lin1t,
          const float* __restrict__ lin2_w, u16* __restrict__ lin2t,
          const float* __restrict__ att1_w, u16* __restrict__ att1t) {
  const int b = blockIdx.x, tid = threadIdx.x;
  if (b < 3072) {
    int i = b * 256 + tid;                     // 8-elem chunk of x
    const float4* p = (const float4*)X + (size_t)i * 2;
    float4 a = p[0], c = p[1];
    uint4 o;
    o.x = f2bf(a.x) | ((unsigned)f2bf(a.y) << 16);
    o.y = f2bf(a.z) | ((unsigned)f2bf(a.w) << 16);
    o.z = f2bf(c.x) | ((unsigned)f2bf(c.y) << 16);
    o.w = f2bf(c.z) | ((unsigned)f2bf(c.w) << 16);
    ((uint4*)Xb)[i] = o;
  } else if (b < 3840) {
    wconv_body(fc1_w, fc1t, 384, 512, (b - 3072) * 256 + tid);
  } else if (b < 4864) {
    wconv_body(wh_w, wht, 512, 512, (b - 3840) * 256 + tid);
  } else if (b < 5888) {
    wconv_body(wt_w, wtt, 512, 512, (b - 4864) * 256 + tid);
  } else if (b < 6912) {
    wconv_body(lin1_w, lin1t, 512, 512, (b - 5888) * 256 + tid);
  } else if (b < 7936) {
    wconv_body(lin2_w, lin2t, 512, 512, (b - 6912) * 256 + tid);
  } else {
    wconv_body(att1_w, att1t, 512, 256, (b - 7936) * 256 + tid);
  }
}

__global__ __launch_bounds__(256)
void colsum_partial(const float* __restrict__ H, float* __restrict__ part) {
  int col = blockIdx.x * 64 + (threadIdx.x & 63);
  int sub = threadIdx.x >> 6;
  int rEnd = blockIdx.y * 512 + 512;
  float s = 0.f;
  for (int r = blockIdx.y * 512 + sub; r < rEnd; r += 4)
    s += H[(size_t)r * DIM + col];
  __shared__ float sh[4][64];
  sh[sub][threadIdx.x & 63] = s;
  __syncthreads();
  if (threadIdx.x < 64) {
    float tot = sh[0][threadIdx.x] + sh[1][threadIdx.x] +
                sh[2][threadIdx.x] + sh[3][threadIdx.x];
    part[(size_t)blockIdx.y * DIM + col] = tot;
  }
}

__global__ void finalize_mean(const float* __restrict__ part,
                              float* __restrict__ mean) {
  int c = threadIdx.x;
  float s = 0.f;
  for (int j = 0; j < 32; j++) s += part[j * DIM + c];
  mean[c] = s * (1.0f / NROWS);
}

// h = (h0 + mean)*0.5, bf16 output only
__global__ __launch_bounds__(256)
void h_fix_bf(const float* __restrict__ H0, const float* __restrict__ mean,
              u16* __restrict__ Hb) {
  int idx = blockIdx.x * 256 + threadIdx.x;         // 8-elem chunk
  int c = (idx * 8) & (DIM - 1);
  const float4* p = (const float4*)H0 + (size_t)idx * 2;
  float4 a = p[0], b = p[1];
  float4 m0 = *(const float4*)(mean + c);
  float4 m1 = *(const float4*)(mean + c + 4);
  a.x = (a.x + m0.x) * 0.5f; a.y = (a.y + m0.y) * 0.5f;
  a.z = (a.z + m0.z) * 0.5f; a.w = (a.w + m0.w) * 0.5f;
  b.x = (b.x + m1.x) * 0.5f; b.y = (b.y + m1.y) * 0.5f;
  b.z = (b.z + m1.z) * 0.5f; b.w = (b.w + m1.w) * 0.5f;
  uint4 o;
  o.x = f2bf(a.x) | ((unsigned)f2bf(a.y) << 16);
  o.y = f2bf(a.z) | ((unsigned)f2bf(a.w) << 16);
  o.z = f2bf(b.x) | ((unsigned)f2bf(b.y) << 16);
  o.w = f2bf(b.z) | ((unsigned)f2bf(b.w) << 16);
  ((uint4*)Hb)[idx] = o;
}

// ---------------------------------------------------------------------------
// bf16 MFMA GEMM (R4-verified): C = act(A@Wt^T + bias), opt +=, opt bf16 store.
// ---------------------------------------------------------------------------
template<int ACT, int ACCUM, int STOREBF>
__global__ __launch_bounds__(256, 2)
void gemm_bf16(const u16* __restrict__ A, const u16* __restrict__ Wt,
               const float* __restrict__ bias, float* __restrict__ C,
               u16* __restrict__ Cb, float bscale, int K, int N) {
  __shared__ char lds[65536];   // A dbuf [0,32K), W dbuf [32K,64K)
  const int tid = threadIdx.x;
  const int w = tid >> 6, l = tid & 63;
  const int l31 = l & 31, lh = l >> 5, lh16 = lh << 4;
  const int qg = w & 1, ng = w >> 1;
  const int swz = (l31 & 7) << 4;
  const int rowBase = blockIdx.y * 128;
  const int colBase = blockIdx.x * 128;
  const int nsteps = K >> 6;

  f32x16 z;
  #pragma unroll
  for (int i = 0; i < 16; i++) z[i] = 0.f;
  f32x16 acc00 = z, acc01 = z, acc10 = z, acc11 = z;

#define GSTAGE(buf_, kc_) do { \
    const int r_ = tid >> 3, j_ = tid & 7; \
    const int js_ = ((j_ ^ (r_ & 7)) << 3); \
    const u16* as_ = A + (size_t)rowBase * K + (kc_); \
    const u16* ws_ = Wt + (size_t)colBase * K + (kc_); \
    char* ab_ = lds + (buf_) * 16384; \
    char* wb_ = lds + 32768 + (buf_) * 16384; \
    _Pragma("unroll") \
    for (int p_ = 0; p_ < 4; ++p_) { \
      __builtin_amdgcn_global_load_lds( \
        (const __attribute__((address_space(1))) void*)(as_ + (size_t)(r_ + 32 * p_) * K + js_), \
        (__attribute__((address_space(3))) void*)(ab_ + w * 1024 + p_ * 4096), 16, 0, 0); \
      __builtin_amdgcn_global_load_lds( \
        (const __attribute__((address_space(1))) void*)(ws_ + (size_t)(r_ + 32 * p_) * K + js_), \
        (__attribute__((address_space(3))) void*)(wb_ + w * 1024 + p_ * 4096), 16, 0, 0); \
    } \
  } while (0)

  GSTAGE(0, 0);
  asm volatile("s_waitcnt vmcnt(0)" ::: "memory");
  sbar();
  #pragma unroll 1
  for (int s = 0; s < nsteps; ++s) {
    const int cur = s & 1;
    if (s + 1 < nsteps) GSTAGE(cur ^ 1, (s + 1) * 64);
    __builtin_amdgcn_sched_barrier(0);
    const char* ab = lds + cur * 16384;
    const char* wb = lds + 32768 + cur * 16384;
    __builtin_amdgcn_s_setprio(1);
    #pragma unroll
    for (int s4 = 0; s4 < 4; ++s4) {
      const int off = (s4 * 32 + lh16) ^ swz;
      bf16x8 am0 = *(const bf16x8*)(ab + (qg * 64 + l31) * 128 + off);
      bf16x8 am1 = *(const bf16x8*)(ab + (qg * 64 + 32 + l31) * 128 + off);
      bf16x8 wn0 = *(const bf16x8*)(wb + (ng * 64 + l31) * 128 + off);
      bf16x8 wn1 = *(const bf16x8*)(wb + (ng * 64 + 32 + l31) * 128 + off);
      acc00 = __builtin_amdgcn_mfma_f32_32x32x16_bf16(wn0, am0, acc00, 0, 0, 0);
      acc01 = __builtin_amdgcn_mfma_f32_32x32x16_bf16(wn1, am0, acc01, 0, 0, 0);
      acc10 = __builtin_amdgcn_mfma_f32_32x32x16_bf16(wn0, am1, acc10, 0, 0, 0);
      acc11 = __builtin_amdgcn_mfma_f32_32x32x16_bf16(wn1, am1, acc11, 0, 0, 0);
    }
    __builtin_amdgcn_s_setprio(0);
    asm volatile("s_waitcnt vmcnt(0)" ::: "memory");
    sbar();
  }
#undef GSTAGE

  // epilogue: spill to LDS (XOR-swizzled cols), then coalesced store
  float* Ls = (float*)lds;
  {
    const int m0 = qg * 64 + l31;
    const int k0 = (m0 & 7) << 2;
    #pragma unroll
    for (int r = 0; r < 16; ++r) {
      const int nd = ng * 64 + (r & 3) + 8 * (r >> 2) + 4 * lh;
      Ls[m0 * 128 + (nd ^ k0)] = acc00[r];
      Ls[m0 * 128 + ((nd + 32) ^ k0)] = acc01[r];
      Ls[(m0 + 32) * 128 + (nd ^ k0)] = acc10[r];
      Ls[(m0 + 32) * 128 + ((nd + 32) ^ k0)] = acc11[r];
    }
  }
  sbar();
  #pragma unroll
  for (int p = 0; p < 16; ++p) {
    int idx = tid + 256 * p;
    int m = idx >> 5, c4 = (idx & 31) << 2;
    float4 v = *(const float4*)&Ls[m * 128 + (c4 ^ ((m & 7) << 2))];
    int col = colBase + c4;
    float4 bv = *(const float4*)&bias[col];
    v.x += bv.x; v.y += bv.y; v.z += bv.z; v.w += bv.w;
    if (ACT) {
      v.x = lrelu_f(v.x); v.y = lrelu_f(v.y);
      v.z = lrelu_f(v.z); v.w = lrelu_f(v.w);
    }
    size_t o = (size_t)(rowBase + m) * N + col;
    if (ACCUM) {
      float4 c0 = *(const float4*)&C[o];
      v.x += c0.x; v.y += c0.y; v.z += c0.z; v.w += c0.w;
    }
    *(float4*)&C[o] = v;
    if (STOREBF) {
      ushort4 q;
      q.x = f2bf(v.x * bscale); q.y = f2bf(v.y * bscale);
      q.z = f2bf(v.z * bscale); q.w = f2bf(v.w * bscale);
      *(ushort4*)&Cb[o] = q;
    }
  }
}

// ---------------------------------------------------------------------------
// Dual GEMM, SHARED A: C1 = A@W1+b1, C2 = A@W2+b2 (no act), each stored f32
// + scaled bf16. K=N=512. 3 staged streams (A,W1,W2), single-buffer drain.
// Index math identical to gemm_bf16 (verified).
// ---------------------------------------------------------------------------
__global__ __launch_bounds__(256, 2)
void gemm_dualA(const u16* __restrict__ A, const u16* __restrict__ W1t,
                const u16* __restrict__ W2t,
                const float* __restrict__ b1, const float* __restrict__ b2,
                float* __restrict__ C1, u16* __restrict__ C1b, float s1,
                float* __restrict__ C2, u16* __restrict__ C2b, float s2) {
  __shared__ char lds[65536];   // A [0,16K) W1 [16K,32K) W2 [32K,48K); Ls 64K
  const int tid = threadIdx.x;
  const int w = tid >> 6, l = tid & 63;
  const int l31 = l & 31, lh = l >> 5, lh16 = lh << 4;
  const int qg = w & 1, ng = w >> 1;
  const int swz = (l31 & 7) << 4;
  const int rowBase = blockIdx.y * 128;
  const int colBase = blockIdx.x * 128;

  f32x16 z;
  #pragma unroll
  for (int i = 0; i < 16; i++) z[i] = 0.f;
  f32x16 p00 = z, p01 = z, p10 = z, p11 = z;
  f32x16 q00 = z, q01 = z, q10 = z, q11 = z;

  #pragma unroll 1
  for (int s = 0; s < 8; ++s) {
    {
      const int r_ = tid >> 3, j_ = tid & 7;
      const int js_ = ((j_ ^ (r_ & 7)) << 3);
      const u16* as_ = A + (size_t)rowBase * DIM + s * 64;
      const u16* w1_ = W1t + (size_t)colBase * DIM + s * 64;
      const u16* w2_ = W2t + (size_t)colBase * DIM + s * 64;
      #pragma unroll
      for (int p_ = 0; p_ < 4; ++p_) {
        __builtin_amdgcn_global_load_lds(
          (const __attribute__((address_space(1))) void*)(as_ + (size_t)(r_ + 32 * p_) * DIM + js_),
          (__attribute__((address_space(3))) void*)(lds + w * 1024 + p_ * 4096), 16, 0, 0);
        __builtin_amdgcn_global_load_lds(
          (const __attribute__((address_space(1))) void*)(w1_ + (size_t)(r_ + 32 * p_) * DIM + js_),
          (__attribute__((address_space(3))) void*)(lds + 16384 + w * 1024 + p_ * 4096), 16, 0, 0);
        __builtin_amdgcn_global_load_lds(
          (const __attribute__((address_space(1))) void*)(w2_ + (size_t)(r_ + 32 * p_) * DIM + js_),
          (__attribute__((address_space(3))) void*)(lds + 32768 + w * 1024 + p_ * 4096), 16, 0, 0);
      }
    }
    asm volatile("s_waitcnt vmcnt(0)" ::: "memory");
    sbar();
    const char* ab = lds;
    const char* w1b = lds + 16384;
    const char* w2b = lds + 32768;
    __builtin_amdgcn_s_setprio(1);
    #pragma unroll
    for (int s4 = 0; s4 < 4; ++s4) {
      const int off = (s4 * 32 + lh16) ^ swz;
      bf16x8 am0 = *(const bf16x8*)(ab + (qg * 64 + l31) * 128 + off);
      bf16x8 am1 = *(const bf16x8*)(ab + (qg * 64 + 32 + l31) * 128 + off);
      bf16x8 x0 = *(const bf16x8*)(w1b + (ng * 64 + l31) * 128 + off);
      bf16x8 x1 = *(const bf16x8*)(w1b + (ng * 64 + 32 + l31) * 128 + off);
      bf16x8 y0 = *(const bf16x8*)(w2b + (ng * 64 + l31) * 128 + off);
      bf16x8 y1 = *(const bf16x8*)(w2b + (ng * 64 + 32 + l31) * 128 + off);
      p00 = __builtin_amdgcn_mfma_f32_32x32x16_bf16(x0, am0, p00, 0, 0, 0);
      p01 = __builtin_amdgcn_mfma_f32_32x32x16_bf16(x1, am0, p01, 0, 0, 0);
      p10 = __builtin_amdgcn_mfma_f32_32x32x16_bf16(x0, am1, p10, 0, 0, 0);
      p11 = __builtin_amdgcn_mfma_f32_32x32x16_bf16(x1, am1, p11, 0, 0, 0);
      q00 = __builtin_amdgcn_mfma_f32_32x32x16_bf16(y0, am0, q00, 0, 0, 0);
      q01 = __builtin_amdgcn_mfma_f32_32x32x16_bf16(y1, am0, q01, 0, 0, 0);
      q10 = __builtin_amdgcn_mfma_f32_32x32x16_bf16(y0, am1, q10, 0, 0, 0);
      q11 = __builtin_amdgcn_mfma_f32_32x32x16_bf16(y1, am1, q11, 0, 0, 0);
    }
    __builtin_amdgcn_s_setprio(0);
    sbar();                                   // reads done before next stage
  }

  float* Ls = (float*)lds;
  const int m0 = qg * 64 + l31;
  const int k0 = (m0 & 7) << 2;
  // ---- pass 1: C1 ----
  #pragma unroll
  for (int r = 0; r < 16; ++r) {
    const int nd = ng * 64 + (r & 3) + 8 * (r >> 2) + 4 * lh;
    Ls[m0 * 128 + (nd ^ k0)] = p00[r];
    Ls[m0 * 128 + ((nd + 32) ^ k0)] = p01[r];
    Ls[(m0 + 32) * 128 + (nd ^ k0)] = p10[r];
    Ls[(m0 + 32) * 128 + ((nd + 32) ^ k0)] = p11[r];
  }
  sbar();
  #pragma unroll
  for (int p = 0; p < 16; ++p) {
    int idx = tid + 256 * p;
    int m = idx >> 5, c4 = (idx & 31) << 2;
    float4 v = *(const float4*)&Ls[m * 128 + (c4 ^ ((m & 7) << 2))];
    int col = colBase + c4;
    float4 bv = *(const float4*)&b1[col];
    v.x += bv.x; v.y += bv.y; v.z += bv.z; v.w += bv.w;
    size_t o = (size_t)(rowBase + m) * DIM + col;
    *(float4*)&C1[o] = v;
    ushort4 qo;
    qo.x = f2bf(v.x * s1); qo.y = f2bf(v.y * s1);
    qo.z = f2bf(v.z * s1); qo.w = f2bf(v.w * s1);
    *(ushort4*)&C1b[o] = qo;
  }
  sbar();
  // ---- pass 2: C2 ----
  #pragma unroll
  for (int r = 0; r < 16; ++r) {
    const int nd = ng * 64 + (r & 3) + 8 * (r >> 2) + 4 * lh;
    Ls[m0 * 128 + (nd ^ k0)] = q00[r];
    Ls[m0 * 128 + ((nd + 32) ^ k0)] = q01[r];
    Ls[(m0 + 32) * 128 + (nd ^ k0)] = q10[r];
    Ls[(m0 + 32) * 128 + ((nd + 32) ^ k0)] = q11[r];
  }
  sbar();
  #pragma unroll
  for (int p = 0; p < 16; ++p) {
    int idx = tid + 256 * p;
    int m = idx >> 5, c4 = (idx & 31) << 2;
    float4 v = *(const float4*)&Ls[m * 128 + (c4 ^ ((m & 7) << 2))];
    int col = colBase + c4;
    float4 bv = *(const float4*)&b2[col];
    v.x += bv.x; v.y += bv.y; v.z += bv.z; v.w += bv.w;
    size_t o = (size_t)(rowBase + m) * DIM + col;
    *(float4*)&C2[o] = v;
    ushort4 qo;
    qo.x = f2bf(v.x * s2); qo.y = f2bf(v.y * s2);
    qo.z = f2bf(v.z * s2); qo.w = f2bf(v.w * s2);
    *(ushort4*)&C2b[o] = qo;
  }
}

// ---------------------------------------------------------------------------
// Dual GEMM, SUMMED: C = lrelu(A1@W1+b1) + lrelu(A2@W2+b2), f32 + bf16 out.
// K=N=512. 4 staged streams, single-buffer drain. Bias+lrelu applied at spill.
// ---------------------------------------------------------------------------
__global__ __launch_bounds__(256, 2)
void gemm_dualsum(const u16* __restrict__ A1, const u16* __restrict__ A2,
                  const u16* __restrict__ W1t, const u16* __restrict__ W2t,
                  const float* __restrict__ b1, const float* __restrict__ b2,
                  float* __restrict__ C, u16* __restrict__ Cb) {
  __shared__ char lds[65536];   // A1 0 | A2 16K | W1 32K | W2 48K; Ls 64K
  const int tid = threadIdx.x;
  const int w = tid >> 6, l = tid & 63;
  const int l31 = l & 31, lh = l >> 5, lh16 = lh << 4;
  const int qg = w & 1, ng = w >> 1;
  const int swz = (l31 & 7) << 4;
  const int rowBase = blockIdx.y * 128;
  const int colBase = blockIdx.x * 128;

  f32x16 z;
  #pragma unroll
  for (int i = 0; i < 16; i++) z[i] = 0.f;
  f32x16 p00 = z, p01 = z, p10 = z, p11 = z;
  f32x16 q00 = z, q01 = z, q10 = z, q11 = z;

  #pragma unroll 1
  for (int s = 0; s < 8; ++s) {
    {
      const int r_ = tid >> 3, j_ = tid & 7;
      const int js_ = ((j_ ^ (r_ & 7)) << 3);
      const u16* a1_ = A1 + (size_t)rowBase * DIM + s * 64;
      const u16* a2_ = A2 + (size_t)rowBase * DIM + s * 64;
      const u16* w1_ = W1t + (size_t)colBase * DIM + s * 64;
      const u16* w2_ = W2t + (size_t)colBase * DIM + s * 64;
      #pragma unroll
      for (int p_ = 0; p_ < 4; ++p_) {
        __builtin_amdgcn_global_load_lds(
          (const __attribute__((address_space(1))) void*)(a1_ + (size_t)(r_ + 32 * p_) * DIM + js_),
          (__attribute__((address_space(3))) void*)(lds + w * 1024 + p_ * 4096), 16, 0, 0);
        __builtin_amdgcn_global_load_lds(
          (const __attribute__((address_space(1))) void*)(a2_ + (size_t)(r_ + 32 * p_) * DIM + js_),
          (__attribute__((address_space(3))) void*)(lds + 16384 + w * 1024 + p_ * 4096), 16, 0, 0);
        __builtin_amdgcn_global_load_lds(
          (const __attribute__((address_space(1))) void*)(w1_ + (size_t)(r_ + 32 * p_) * DIM + js_),
          (__attribute__((address_space(3))) void*)(lds + 32768 + w * 1024 + p_ * 4096), 16, 0, 0);
        __builtin_amdgcn_global_load_lds(
          (const __attribute__((address_space(1))) void*)(w2_ + (size_t)(r_ + 32 * p_) * DIM + js_),
          (__attribute__((address_space(3))) void*)(lds + 49152 + w * 1024 + p_ * 4096), 16, 0, 0);
      }
    }
    asm volatile("s_waitcnt vmcnt(0)" ::: "memory");
    sbar();
    const char* a1b = lds;
    const char* a2b = lds + 16384;
    const char* w1b = lds + 32768;
    const char* w2b = lds + 49152;
    __builtin_amdgcn_s_setprio(1);
    #pragma unroll
    for (int s4 = 0; s4 < 4; ++s4) {
      const int off = (s4 * 32 + lh16) ^ swz;
      bf16x8 am0 = *(const bf16x8*)(a1b + (qg * 64 + l31) * 128 + off);
      bf16x8 am1 = *(const bf16x8*)(a1b + (qg * 64 + 32 + l31) * 128 + off);
      bf16x8 bm0 = *(const bf16x8*)(a2b + (qg * 64 + l31) * 128 + off);
      bf16x8 bm1 = *(const bf16x8*)(a2b + (qg * 64 + 32 + l31) * 128 + off);
      bf16x8 x0 = *(const bf16x8*)(w1b + (ng * 64 + l31) * 128 + off);
      bf16x8 x1 = *(const bf16x8*)(w1b + (ng * 64 + 32 + l31) * 128 + off);
      bf16x8 y0 = *(const bf16x8*)(w2b + (ng * 64 + l31) * 128 + off);
      bf16x8 y1 = *(const bf16x8*)(w2b + (ng * 64 + 32 + l31) * 128 + off);
      p00 = __builtin_amdgcn_mfma_f32_32x32x16_bf16(x0, am0, p00, 0, 0, 0);
      p01 = __builtin_amdgcn_mfma_f32_32x32x16_bf16(x1, am0, p01, 0, 0, 0);
      p10 = __builtin_amdgcn_mfma_f32_32x32x16_bf16(x0, am1, p10, 0, 0, 0);
      p11 = __builtin_amdgcn_mfma_f32_32x32x16_bf16(x1, am1, p11, 0, 0, 0);
      q00 = __builtin_amdgcn_mfma_f32_32x32x16_bf16(y0, bm0, q00, 0, 0, 0);
      q01 = __builtin_amdgcn_mfma_f32_32x32x16_bf16(y1, bm0, q01, 0, 0, 0);
      q10 = __builtin_amdgcn_mfma_f32_32x32x16_bf16(y0, bm1, q10, 0, 0, 0);
      q11 = __builtin_amdgcn_mfma_f32_32x32x16_bf16(y1, bm1, q11, 0, 0, 0);
    }
    __builtin_amdgcn_s_setprio(0);
    sbar();
  }

  // epilogue: combined value at spill (bias + lrelu + sum), then coalesced
  float* Ls = (float*)lds;
  const int m0 = qg * 64 + l31;
  const int k0 = (m0 & 7) << 2;
  #pragma unroll
  for (int r = 0; r < 16; ++r) {
    const int nd = ng * 64 + (r & 3) + 8 * (r >> 2) + 4 * lh;
    const int c0 = colBase + nd, c1 = colBase + nd + 32;
    Ls[m0 * 128 + (nd ^ k0)] =
        lrelu_f(p00[r] + b1[c0]) + lrelu_f(q00[r] + b2[c0]);
    Ls[m0 * 128 + ((nd + 32) ^ k0)] =
        lrelu_f(p01[r] + b1[c1]) + lrelu_f(q01[r] + b2[c1]);
    Ls[(m0 + 32) * 128 + (nd ^ k0)] =
        lrelu_f(p10[r] + b1[c0]) + lrelu_f(q10[r] + b2[c0]);
    Ls[(m0 + 32) * 128 + ((nd + 32) ^ k0)] =
        lrelu_f(p11[r] + b1[c1]) + lrelu_f(q11[r] + b2[c1]);
  }
  sbar();
  #pragma unroll
  for (int p = 0; p < 16; ++p) {
    int idx = tid + 256 * p;
    int m = idx >> 5, c4 = (idx & 31) << 2;
    float4 v = *(const float4*)&Ls[m * 128 + (c4 ^ ((m & 7) << 2))];
    int col = colBase + c4;
    size_t o = (size_t)(rowBase + m) * DIM + col;
    *(float4*)&C[o] = v;
    ushort4 qo;
    qo.x = f2bf(v.x); qo.y = f2bf(v.y); qo.z = f2bf(v.z); qo.w = f2bf(v.w);
    *(ushort4*)&Cb[o] = qo;
  }
}

// ---------------------------------------------------------------------------
// MFMA attn-logit + per-row top-6 — R9-verified: shared-B, 128k phases,
// triple buffer, counted vmcnt(4). 512 blocks x 256 thr, 2 blocks/CU, 48 KB.
// ---------------------------------------------------------------------------
#define T6(tv, tix, vv, cc) do { float v_ = (vv); \
  if (v_ > tv[5]) { tv[5] = v_; tix[5] = (cc); \
    if (tv[5] > tv[4]) { float t=tv[4];tv[4]=tv[5];tv[5]=t; int q=tix[4];tix[4]=tix[5];tix[5]=q; } \
    if (tv[4] > tv[3]) { float t=tv[3];tv[3]=tv[4];tv[4]=t; int q=tix[3];tix[3]=tix[4];tix[4]=q; } \
    if (tv[3] > tv[2]) { float t=tv[2];tv[2]=tv[3];tv[3]=t; int q=tix[2];tix[2]=tix[3];tix[3]=q; } \
    if (tv[2] > tv[1]) { float t=tv[1];tv[1]=tv[2];tv[2]=t; int q=tix[1];tix[1]=tix[2];tix[2]=q; } \
    if (tv[1] > tv[0]) { float t=tv[0];tv[0]=tv[1];tv[1]=t; int q=tix[0];tix[0]=tix[1];tix[1]=q; } \
  } } while (0)

__global__ __launch_bounds__(256, 2)
void attn_topk_mfma(const u16* __restrict__ EHb, const u16* __restrict__ ETb,
                    float* __restrict__ TWp, int* __restrict__ TIp) {
  __shared__ char lds[49152];            // 3 shared B buffers x 16 KB
  const int tid = threadIdx.x;
  const int w = tid >> 6, l = tid & 63;
  const int l31 = l & 31, lh = l >> 5;

  const int bid = blockIdx.x;
  const int xcd = bid & 7;
  const int split = xcd & 3;
  const int rowBase = ((xcd >> 2) * 64 + (bid >> 3)) * 128;
  const int qrow = rowBase + w * 32 + l31;     // this lane's query row

  bf16x8 areg[32];
  {
    const u16* ap = EHb + (size_t)qrow * DIM + lh * 8;
    #pragma unroll
    for (int ks = 0; ks < 32; ++ks)
      areg[ks] = *(const bf16x8*)(ap + ks * 16);
  }

  f32x16 z;
  #pragma unroll
  for (int i = 0; i < 16; i++) z[i] = 0.f;
  f32x16 acc0 = z, acc1 = z;

  float tv[KSEL]; int tix[KSEL];
  #pragma unroll
  for (int k = 0; k < KSEL; k++) { tv[k] = -INFINITY; tix[k] = 0x7fffffff; }

#define STAGE(bufi_, ph_) do { \
    const int ct_ = (ph_) >> 2, kc_ = (ph_) & 3; \
    char* db_ = lds + (bufi_) * 16384; \
    const u16* bs_ = ETb + (size_t)(split * COLS_PER_SPLIT + ct_ * 64) * DIM + kc_ * 128; \
    _Pragma("unroll") \
    for (int p_ = 0; p_ < 4; ++p_) { \
      const int c_ = (w * 4 + p_) * 64 + l; \
      const int rn_ = c_ >> 4; \
      const int js_ = ((c_ & 15) ^ (rn_ & 15)) << 3; \
      __builtin_amdgcn_global_load_lds( \
        (const __attribute__((address_space(1))) void*)(bs_ + (size_t)rn_ * DIM + js_), \
        (__attribute__((address_space(3))) void*)(db_ + (w * 4 + p_) * 1024), 16, 0, 0); \
    } \
  } while (0)

  int bufr = 0;
  STAGE(0, 0);
  STAGE(1, 1);
  asm volatile("s_waitcnt vmcnt(4)" ::: "memory");   // stage(0) landed

  #pragma unroll 1
  for (int ct = 0; ct < 64; ++ct) {
    #pragma unroll
    for (int kc = 0; kc < 4; ++kc) {
      sbar();                                  // stage(p) landed; p-1 reads done
      const char* db = lds + bufr * 16384;
      __builtin_amdgcn_s_setprio(1);
      #pragma unroll
      for (int s = 0; s < 8; ++s) {
        const int j0 = ((s * 2 + lh) ^ (l31 & 15)) * 16;
        bf16x8 bn0 = *(const bf16x8*)(db + l31 * 256 + j0);
        const int r1 = 32 + l31;
        const int j1 = ((s * 2 + lh) ^ (r1 & 15)) * 16;
        bf16x8 bn1 = *(const bf16x8*)(db + r1 * 256 + j1);
        acc0 = __builtin_amdgcn_mfma_f32_32x32x16_bf16(bn0, areg[kc * 8 + s], acc0, 0, 0, 0);
        acc1 = __builtin_amdgcn_mfma_f32_32x32x16_bf16(bn1, areg[kc * 8 + s], acc1, 0, 0, 0);
      }
      __builtin_amdgcn_s_setprio(0);
      if (kc == 3) {
        const int cb = split * COLS_PER_SPLIT + ct * 64 + 4 * lh;
        #pragma unroll
        for (int r = 0; r < 16; ++r) {
          const int nd = cb + (r & 3) + 8 * (r >> 2);
          T6(tv, tix, acc0[r], nd);
          T6(tv, tix, acc1[r], nd + 32);
        }
        acc0 = z; acc1 = z;
      }
      __builtin_amdgcn_sched_barrier(0);
      {
        const int p = ct * 4 + kc;
        if (p + 2 < 256) {
          const int bs = (bufr >= 1) ? bufr - 1 : bufr + 2;   // (bufr+2)%3
          STAGE(bs, p + 2);
        }
        if (p < 254) { asm volatile("s_waitcnt vmcnt(4)" ::: "memory"); }
        else         { asm volatile("s_waitcnt vmcnt(0)" ::: "memory"); }
      }
      bufr = (bufr == 2) ? 0 : bufr + 1;
    }
  }
#undef STAGE

  // merge the two lh-half lists for this q-row (partner lane = l ^ 32)
  {
    float pv[KSEL]; int pi[KSEL];
    #pragma unroll
    for (int k = 0; k < KSEL; k++) {
      pv[k] = __shfl_xor(tv[k], 32);
      pi[k] = __shfl_xor(tix[k], 32);
    }
    #pragma unroll
    for (int k = 0; k < KSEL; k++) {
      float cv = pv[k]; int ci = pi[k];
      if ((cv > tv[5]) || (cv == tv[5] && ci < tix[5])) {
        tv[5] = cv; tix[5] = ci;
        if ((tv[5] > tv[4]) || (tv[5] == tv[4] && tix[5] < tix[4])) {
          float t = tv[4]; tv[4] = tv[5]; tv[5] = t;
          int q = tix[4]; tix[4] = tix[5]; tix[5] = q; }
        if ((tv[4] > tv[3]) || (tv[4] == tv[3] && tix[4] < tix[3])) {
          float t = tv[3]; tv[3] = tv[4]; tv[4] = t;
          int q = tix[3]; tix[3] = tix[4]; tix[4] = q; }
        if ((tv[3] > tv[2]) || (tv[3] == tv[2] && tix[3] < tix[2])) {
          float t = tv[2]; tv[2] = tv[3]; tv[3] = t;
          int q = tix[2]; tix[2] = tix[3]; tix[3] = q; }
        if ((tv[2] > tv[1]) || (tv[2] == tv[1] && tix[2] < tix[1])) {
          float t = tv[1]; tv[1] = tv[2]; tv[2] = t;
          int q = tix[1]; tix[1] = tix[2]; tix[2] = q; }
        if ((tv[1] > tv[0]) || (tv[1] == tv[0] && tix[1] < tix[0])) {
          float t = tv[0]; tv[0] = tv[1]; tv[1] = t;
          int q = tix[0]; tix[0] = tix[1]; tix[1] = q; }
      }
    }
  }
  if (lh == 0) {
    size_t o = ((size_t)split * NROWS + qrow) * KSEL;
    #pragma unroll
    for (int k = 0; k < KSEL; k++) { TWp[o + k] = tv[k]; TIp[o + k] = tix[k]; }
  }
}

// ---------------------------------------------------------------------------
// Neighbor aggregation + inline 4-split top-6 merge. One wave per row.
// ---------------------------------------------------------------------------
__global__ __launch_bounds__(256)
void neighbor_kernel(const float* __restrict__ EH, const float* __restrict__ ET,
                     const float* __restrict__ TWp, const int* __restrict__ TIp,
                     u16* __restrict__ SINb, u16* __restrict__ BINb) {
  const int lane = threadIdx.x & 63;
  const int row = blockIdx.x * 4 + (threadIdx.x >> 6);
  const float* eh = EH + (size_t)row * DIM;
  float ehv[8];
  #pragma unroll
  for (int u = 0; u < 8; u++) ehv[u] = eh[u * 64 + lane];

  float tw[KSEL]; int ti[KSEL];
  #pragma unroll
  for (int k = 0; k < KSEL; k++) { tw[k] = -INFINITY; ti[k] = 0x7fffffff; }
  #pragma unroll
  for (int s = 0; s < NSPLIT; s++) {
    size_t o = ((size_t)s * NROWS + row) * KSEL;
    #pragma unroll
    for (int k = 0; k < KSEL; k++) {
      float cv = TWp[o + k]; int ci = TIp[o + k];
      if ((cv > tw[5]) || (cv == tw[5] && ci < ti[5])) {
        tw[5] = cv; ti[5] = ci;
        if ((tw[5] > tw[4]) || (tw[5] == tw[4] && ti[5] < ti[4])) {
          float t = tw[4]; tw[4] = tw[5]; tw[5] = t;
          int q = ti[4]; ti[4] = ti[5]; ti[5] = q; }
        if ((tw[4] > tw[3]) || (tw[4] == tw[3] && ti[4] < ti[3])) {
          float t = tw[3]; tw[3] = tw[4]; tw[4] = t;
          int q = ti[3]; ti[3] = ti[4]; ti[4] = q; }
        if ((tw[3] > tw[2]) || (tw[3] == tw[2] && ti[3] < ti[2])) {
          float t = tw[2]; tw[2] = tw[3]; tw[3] = t;
          int q = ti[2]; ti[2] = ti[3]; ti[3] = q; }
        if ((tw[2] > tw[1]) || (tw[2] == tw[1] && ti[2] < ti[1])) {
          float t = tw[1]; tw[1] = tw[2]; tw[2] = t;
          int q = ti[1]; ti[1] = ti[2]; ti[2] = q; }
        if ((tw[1] > tw[0]) || (tw[1] == tw[0] && ti[1] < ti[0])) {
          float t = tw[0]; tw[0] = tw[1]; tw[1] = t;
          int q = ti[0]; ti[0] = ti[1]; ti[1] = q; }
      }
    }
  }

  float m = tw[0];
  #pragma unroll
  for (int k = 1; k < KSEL; k++) m = fmaxf(m, tw[k]);
  float p[KSEL], ps = 0.f;
  #pragma unroll
  for (int k = 0; k < KSEL; k++) { p[k] = expf(tw[k] - m); ps += p[k]; }
  float inv = 1.f / ps;
  #pragma unroll
  for (int k = 0; k < KSEL; k++) p[k] *= inv;

  float nb[KSEL][8];
  float kaw[KSEL];
  #pragma unroll
  for (int k = 0; k < KSEL; k++) {
    const float* et = ET + (size_t)ti[k] * DIM;
    float snb = 0.f, sg = 0.f;
    #pragma unroll
    for (int u = 0; u < 8; u++) {
      float nbv = et[u * 64 + lane];
      nb[k][u] = nbv;
      float ehr = p[k] * nbv + (1.f - p[k]) * ehv[u];
      float g = tanhf(ehv[u] + ehr);
      snb += nbv; sg += g;
    }
    #pragma unroll
    for (int off = 32; off > 0; off >>= 1) {
      snb += __shfl_xor(snb, off);
      sg  += __shfl_xor(sg, off);
    }
    kaw[k] = snb * sg;
  }
  float km = kaw[0];
  #pragma unroll
  for (int k = 1; k < KSEL; k++) km = fmaxf(km, kaw[k]);
  float kp[KSEL], ks = 0.f;
  #pragma unroll
  for (int k = 0; k < KSEL; k++) { kp[k] = expf(kaw[k] - km); ks += kp[k]; }
  float kinv = 1.f / ks;
  #pragma unroll
  for (int k = 0; k < KSEL; k++) kp[k] *= kinv;

  #pragma unroll
  for (int u = 0; u < 8; u++) {
    float enh = 0.f;
    #pragma unroll
    for (int k = 0; k < KSEL; k++) enh += kp[k] * nb[k][u];
    size_t o = (size_t)row * DIM + u * 64 + lane;
    SINb[o] = f2bf(ehv[u] + enh);
    BINb[o] = f2bf(ehv[u] * enh);
  }
}

__global__ __launch_bounds__(256)
void att2_kernel(const float* __restrict__ HID, const float* __restrict__ w2,
                 const float* __restrict__ b2, float* __restrict__ ASC) {
  const int lane = threadIdx.x & 63;
  const int row = blockIdx.x * 4 + (threadIdx.x >> 6);
  float4 hv = ((const float4*)(HID + (size_t)row * 256))[lane];
  float4 wv = ((const float4*)w2)[lane];
  float s = hv.x * wv.x + hv.y * wv.y + hv.z * wv.z + hv.w * wv.w;
  #pragma unroll
  for (int off = 32; off > 0; off >>= 1) s += __shfl_xor(s, off);
  if (lane == 0) ASC[row] = s + b2[0];
}

__global__ __launch_bounds__(1024)
void areduce(const float* __restrict__ ASC, float* __restrict__ stats) {
  __shared__ float sm[1024];
  int t = threadIdx.x;
  float m = -INFINITY;
  for (int i = t; i < NROWS; i += 1024) m = fmaxf(m, ASC[i]);
  sm[t] = m; __syncthreads();
  for (int s = 512; s > 0; s >>= 1) {
    if (t < s) sm[t] = fmaxf(sm[t], sm[t + s]);
    __syncthreads();
  }
  float mx = sm[0]; __syncthreads();
  float sum = 0.f;
  for (int i = t; i < NROWS; i += 1024) sum += expf(ASC[i] - mx);
  sm[t] = sum; __syncthreads();
  for (int s = 512; s > 0; s >>= 1) {
    if (t < s) sm[t] += sm[t + s];
    __syncthreads();
  }
  if (t == 0) { stats[0] = mx; stats[1] = sm[0]; }
}

__global__ __launch_bounds__(256)
void pooled_partial(const float* __restrict__ EMB, const float* __restrict__ ASC,
                    const float* __restrict__ stats, float* __restrict__ part) {
  int col = blockIdx.x * 64 + (threadIdx.x & 63);
  int sub = threadIdx.x >> 6;
  float mx = stats[0];
  int rEnd = blockIdx.y * 512 + 512;
  float s = 0.f;
  for (int r = blockIdx.y * 512 + sub; r < rEnd; r += 4)
    s += expf(ASC[r] - mx) * EMB[(size_t)r * DIM + col];
  __shared__ float sh[4][64];
  sh[sub][threadIdx.x & 63] = s;
  __syncthreads();
  if (threadIdx.x < 64) {
    float tot = sh[0][threadIdx.x] + sh[1][threadIdx.x] +
                sh[2][threadIdx.x] + sh[3][threadIdx.x];
    part[(size_t)blockIdx.y * DIM + col] = tot;
  }
}

__global__ __launch_bounds__(512)
void final_kernel(const float* __restrict__ part, const float* __restrict__ stats,
                  const float* __restrict__ ln_g, const float* __restrict__ ln_b,
                  const float* __restrict__ fc_w, const float* __restrict__ fc_b,
                  float* __restrict__ out) {
  __shared__ float sh[512];
  int t = threadIdx.x;
  float s = 0.f;
  for (int j = 0; j < 32; j++) s += part[j * DIM + t];
  float pooled = s / stats[1];
  sh[t] = pooled; __syncthreads();
  for (int off = 256; off > 0; off >>= 1) {
    if (t < off) sh[t] += sh[t + off];
    __syncthreads();
  }
  float mu = sh[0] * (1.f / DIM); __syncthreads();
  float dv = pooled - mu;
  sh[t] = dv * dv; __syncthreads();
  for (int off = 256; off > 0; off >>= 1) {
    if (t < off) sh[t] += sh[t + off];
    __syncthreads();
  }
  float var = sh[0] * (1.f / DIM); __syncthreads();
  float normed = dv * rsqrtf(var + 1e-5f) * ln_g[t] + ln_b[t];
  sh[t] = normed * fc_w[t * 2 + 0]; __syncthreads();
  for (int off = 256; off > 0; off >>= 1) {
    if (t < off) sh[t] += sh[t + off];
    __syncthreads();
  }
  float l0 = sh[0] + fc_b[0]; __syncthreads();
  sh[t] = normed * fc_w[t * 2 + 1]; __syncthreads();
  for (int off = 256; off > 0; off >>= 1) {
    if (t < off) sh[t] += sh[t + off];
    __syncthreads();
  }
  float l1 = sh[0] + fc_b[1];
  if (t == 0) {
    float mm = fmaxf(l0, l1);
    float e0 = expf(l0 - mm), e1 = expf(l1 - mm);
    float si = 1.f / (e0 + e1);
    out[0] = l0; out[1] = l1; out[2] = e0 * si; out[3] = e1 * si;
  }
}

// ---------------------------------------------------------------------------
extern "C" void kernel_launch(void* const* d_in, const int* in_sizes, int n_in,
                              void* d_out, int out_size, void* d_ws, size_t ws_size,
                              hipStream_t stream) {
  (void)in_sizes; (void)n_in; (void)out_size; (void)ws_size;
  const float* x      = (const float*)d_in[0];
  const float* fc1_w  = (const float*)d_in[1];
  const float* fc1_b  = (const float*)d_in[2];
  const float* wh_w   = (const float*)d_in[3];
  const float* wh_b   = (const float*)d_in[4];
  const float* wt_w   = (const float*)d_in[5];
  const float* wt_b   = (const float*)d_in[6];
  const float* lin1_w = (const float*)d_in[7];
  const float* lin1_b = (const float*)d_in[8];
  const float* lin2_w = (const float*)d_in[9];
  const float* lin2_b = (const float*)d_in[10];
  const float* att1_w = (const float*)d_in[11];
  const float* att1_b = (const float*)d_in[12];
  const float* att2_w = (const float*)d_in[13];
  const float* att2_b = (const float*)d_in[14];
  const float* ln_g   = (const float*)d_in[15];
  const float* ln_b   = (const float*)d_in[16];
  const float* fc_w   = (const float*)d_in[17];
  const float* fc_b   = (const float*)d_in[18];
  float* out = (float*)d_out;

  char* ws = (char*)d_ws;
  float* B0   = (float*)(ws);                       // h0 -> HID
  float* B1   = (float*)(ws + 33554432);            // [xb] -> e_h
  float* B2   = (float*)(ws + 67108864);            // e_t -> emb
  float* TWp  = (float*)(ws + 100663296);
  int*   TIp  = (int*)  (ws + 100663296 + 1572864);
  float* part = (float*)(ws + 100663296 + 3145728 + 786432);
  float* mean = (float*)(ws + 100663296 + 3145728 + 786432 + 65536);
  float* ascr = (float*)(ws + 100663296 + 3145728 + 786432 + 65536 + 2048);
  float* stats= (float*)(ws + 100663296 + 3145728 + 786432 + 65536 + 2048 + 65536);
  u16*   hb   = (u16*)(ws + 104732672);             // -> embb
  u16*   EHb  = (u16*)(ws + 104732672 + 16777216);  // -> sinb
  u16*   ETb  = (u16*)(ws + 104732672 + 33554432);  // -> binb
  u16*   WT   = (u16*)(ws + 104732672 + 50331648);  // transposed bf16 weights
  u16* fc1t = WT;
  u16* wht  = fc1t + 196608;
  u16* wtt  = wht + 262144;
  u16* lin1t= wtt + 262144;
  u16* lin2t= lin1t + 262144;
  u16* att1t= lin2t + 262144;
  u16* xb   = (u16*)B1;      // temp in B1 region, dead before e_h written
  u16* sinb = EHb;           // reuse after attn
  u16* binb = ETb;
  u16* embb = hb;

  // 0. all bf16 conversions in one launch
  prep<<<8448, 256, 0, stream>>>(x, xb, fc1_w, fc1t, wh_w, wht, wt_w, wtt,
                                 lin1_w, lin1t, lin2_w, lin2t, att1_w, att1t);
  // 1. h0 = lrelu(x @ fc1_w + b)
  gemm_bf16<1,0,0><<<dim3(4,128), 256, 0, stream>>>(xb, fc1t, fc1_b, B0, nullptr, 1.f, 384, 512);
  // 2-4. column mean; hb = bf16((h0+mean)*0.5)
  colsum_partial<<<dim3(8,32), 256, 0, stream>>>(B0, part);
  finalize_mean<<<1, 512, 0, stream>>>(part, mean);
  h_fix_bf<<<4096, 256, 0, stream>>>(B0, mean, hb);
  // 5. e_h & e_t in ONE dual-GEMM (shared A): f32 + bf16 (EHb scaled)
  gemm_dualA<<<dim3(4,128), 256, 0, stream>>>(hb, wht, wtt, wh_b, wt_b,
                                              B1, EHb, ATT_SCALE, B2, ETb, 1.f);
  // 6. fused MFMA attn-logit + top-6 per split (R9 pipeline), 4-slot partials
  attn_topk_mfma<<<512, 256, 0, stream>>>(EHb, ETb, TWp, TIp);
  // 7. neighbor aggregation (inline 4-split merge) -> bf16 s_in / b_in
  neighbor_kernel<<<4096, 256, 0, stream>>>(B1, B2, TWp, TIp, sinb, binb);
  // 8. emb = lrelu(sin@lin1+b1) + lrelu(bin@lin2+b2) in ONE dual-GEMM
  gemm_dualsum<<<dim3(4,128), 256, 0, stream>>>(sinb, binb, lin1t, lin2t,
                                                lin1_b, lin2_b, B2, embb);
  // 9. hidden = lrelu(emb@att1+b) -> B0 f32
  gemm_bf16<1,0,0><<<dim3(2,128), 256, 0, stream>>>(embb, att1t, att1_b, B0, nullptr, 1.f, 512, 256);
  // 10-13. readout
  att2_kernel<<<4096, 256, 0, stream>>>(B0, att2_w, att2_b, ascr);
  areduce<<<1, 1024, 0, stream>>>(ascr, stats);
  pooled_partial<<<dim3(8,32), 256, 0, stream>>>(B2, ascr, stats, part);
  final_kernel<<<1, 512, 0, stream>>>(part, stats, ln_g, ln_b, fc_w, fc_b, out);
}

// Round 12
// 581.668 us; speedup vs baseline: 1.5914x; 1.0107x over previous
//
#include <hip/hip_runtime.h>
#include <math.h>

#define NROWS 16384
#define DIN   384
#define DIM   512
#define KSEL  6
#define NSPLIT 4
#define COLS_PER_SPLIT (NROWS / NSPLIT)   // 4096
#define ATT_SCALE 0.044194173824159216f   // 512^-0.5

typedef unsigned short u16;
typedef __attribute__((ext_vector_type(8))) short bf16x8;
typedef __attribute__((ext_vector_type(16))) float f32x16;

static __device__ __forceinline__ float lrelu_f(float v) {
  return v > 0.f ? v : 0.01f * v;
}

static __device__ __forceinline__ u16 f2bf(float f) {  // RNE f32->bf16
  unsigned u = __float_as_uint(f);
  unsigned r = (u + 0x7FFFu + ((u >> 16) & 1u)) >> 16;
  return (u16)r;
}

static __device__ __forceinline__ float bf2f(u16 v) {
  return __uint_as_float(((unsigned)v) << 16);
}

static __device__ __forceinline__ void sbar() {
  asm volatile("" ::: "memory");
  __builtin_amdgcn_s_barrier();
  asm volatile("" ::: "memory");
}

// ---------------------------------------------------------------------------
// prep: all f32->bf16 conversions in ONE launch (input + 6 transposed weights)
// ---------------------------------------------------------------------------
static __device__ __forceinline__ void wconv_body(const float* W, u16* Wt,
                                                  int K, int N, int t) {
  if (t >= K * N) return;
  int k = t / N, n = t - k * N;
  Wt[(size_t)n * K + k] = f2bf(W[t]);
}

__global__ __launch_bounds__(256)
void prep(const float* __restrict__ X, u16* __restrict__ Xb,
          const float* __restrict__ fc1_w, u16* __restrict__ fc1t,
          const float* __restrict__ wh_w, u16* __restrict__ wht,
          const float* __restrict__ wt_w, u16* __restrict__ wtt,
          const float* __restrict__ lin1_w, u16* __restrict__ lin1t,
          const float* __restrict__ lin2_w, u16* __restrict__ lin2t,
          const float* __restrict__ att1_w, u16* __restrict__ att1t) {
  const int b = blockIdx.x, tid = threadIdx.x;
  if (b < 3072) {
    int i = b * 256 + tid;                     // 8-elem chunk of x
    const float4* p = (const float4*)X + (size_t)i * 2;
    float4 a = p[0], c = p[1];
    uint4 o;
    o.x = f2bf(a.x) | ((unsigned)f2bf(a.y) << 16);
    o.y = f2bf(a.z) | ((unsigned)f2bf(a.w) << 16);
    o.z = f2bf(c.x) | ((unsigned)f2bf(c.y) << 16);
    o.w = f2bf(c.z) | ((unsigned)f2bf(c.w) << 16);
    ((uint4*)Xb)[i] = o;
  } else if (b < 3840) {
    wconv_body(fc1_w, fc1t, 384, 512, (b - 3072) * 256 + tid);
  } else if (b < 4864) {
    wconv_body(wh_w, wht, 512, 512, (b - 3840) * 256 + tid);
  } else if (b < 5888) {
    wconv_body(wt_w, wtt, 512, 512, (b - 4864) * 256 + tid);
  } else if (b < 6912) {
    wconv_body(lin1_w, lin1t, 512, 512, (b - 5888) * 256 + tid);
  } else if (b < 7936) {
    wconv_body(lin2_w, lin2t, 512, 512, (b - 6912) * 256 + tid);
  } else {
    wconv_body(att1_w, att1t, 512, 256, (b - 7936) * 256 + tid);
  }
}

__global__ __launch_bounds__(256)
void colsum_partial(const float* __restrict__ H, float* __restrict__ part) {
  int col = blockIdx.x * 64 + (threadIdx.x & 63);
  int sub = threadIdx.x >> 6;
  int rEnd = blockIdx.y * 512 + 512;
  float s = 0.f;
  for (int r = blockIdx.y * 512 + sub; r < rEnd; r += 4)
    s += H[(size_t)r * DIM + col];
  __shared__ float sh[4][64];
  sh[sub][threadIdx.x & 63] = s;
  __syncthreads();
  if (threadIdx.x < 64) {
    float tot = sh[0][threadIdx.x] + sh[1][threadIdx.x] +
                sh[2][threadIdx.x] + sh[3][threadIdx.x];
    part[(size_t)blockIdx.y * DIM + col] = tot;
  }
}

__global__ void finalize_mean(const float* __restrict__ part,
                              float* __restrict__ mean) {
  int c = threadIdx.x;
  float s = 0.f;
  for (int j = 0; j < 32; j++) s += part[j * DIM + c];
  mean[c] = s * (1.0f / NROWS);
}

// h = (h0 + mean)*0.5, bf16 output only
__global__ __launch_bounds__(256)
void h_fix_bf(const float* __restrict__ H0, const float* __restrict__ mean,
              u16* __restrict__ Hb) {
  int idx = blockIdx.x * 256 + threadIdx.x;         // 8-elem chunk
  int c = (idx * 8) & (DIM - 1);
  const float4* p = (const float4*)H0 + (size_t)idx * 2;
  float4 a = p[0], b = p[1];
  float4 m0 = *(const float4*)(mean + c);
  float4 m1 = *(const float4*)(mean + c + 4);
  a.x = (a.x + m0.x) * 0.5f; a.y = (a.y + m0.y) * 0.5f;
  a.z = (a.z + m0.z) * 0.5f; a.w = (a.w + m0.w) * 0.5f;
  b.x = (b.x + m1.x) * 0.5f; b.y = (b.y + m1.y) * 0.5f;
  b.z = (b.z + m1.z) * 0.5f; b.w = (b.w + m1.w) * 0.5f;
  uint4 o;
  o.x = f2bf(a.x) | ((unsigned)f2bf(a.y) << 16);
  o.y = f2bf(a.z) | ((unsigned)f2bf(a.w) << 16);
  o.z = f2bf(b.x) | ((unsigned)f2bf(b.y) << 16);
  o.w = f2bf(b.z) | ((unsigned)f2bf(b.w) << 16);
  ((uint4*)Hb)[idx] = o;
}

// ---------------------------------------------------------------------------
// bf16 MFMA GEMM (R4-verified): C = act(A@Wt^T + bias); STOREF32 / STOREBF.
// ---------------------------------------------------------------------------
template<int ACT, int STOREBF, int STOREF32>
__global__ __launch_bounds__(256, 2)
void gemm_bf16(const u16* __restrict__ A, const u16* __restrict__ Wt,
               const float* __restrict__ bias, float* __restrict__ C,
               u16* __restrict__ Cb, float bscale, int K, int N) {
  __shared__ char lds[65536];   // A dbuf [0,32K), W dbuf [32K,64K)
  const int tid = threadIdx.x;
  const int w = tid >> 6, l = tid & 63;
  const int l31 = l & 31, lh = l >> 5, lh16 = lh << 4;
  const int qg = w & 1, ng = w >> 1;
  const int swz = (l31 & 7) << 4;
  const int rowBase = blockIdx.y * 128;
  const int colBase = blockIdx.x * 128;
  const int nsteps = K >> 6;

  f32x16 z;
  #pragma unroll
  for (int i = 0; i < 16; i++) z[i] = 0.f;
  f32x16 acc00 = z, acc01 = z, acc10 = z, acc11 = z;

#define GSTAGE(buf_, kc_) do { \
    const int r_ = tid >> 3, j_ = tid & 7; \
    const int js_ = ((j_ ^ (r_ & 7)) << 3); \
    const u16* as_ = A + (size_t)rowBase * K + (kc_); \
    const u16* ws_ = Wt + (size_t)colBase * K + (kc_); \
    char* ab_ = lds + (buf_) * 16384; \
    char* wb_ = lds + 32768 + (buf_) * 16384; \
    _Pragma("unroll") \
    for (int p_ = 0; p_ < 4; ++p_) { \
      __builtin_amdgcn_global_load_lds( \
        (const __attribute__((address_space(1))) void*)(as_ + (size_t)(r_ + 32 * p_) * K + js_), \
        (__attribute__((address_space(3))) void*)(ab_ + w * 1024 + p_ * 4096), 16, 0, 0); \
      __builtin_amdgcn_global_load_lds( \
        (const __attribute__((address_space(1))) void*)(ws_ + (size_t)(r_ + 32 * p_) * K + js_), \
        (__attribute__((address_space(3))) void*)(wb_ + w * 1024 + p_ * 4096), 16, 0, 0); \
    } \
  } while (0)

  GSTAGE(0, 0);
  asm volatile("s_waitcnt vmcnt(0)" ::: "memory");
  sbar();
  #pragma unroll 1
  for (int s = 0; s < nsteps; ++s) {
    const int cur = s & 1;
    if (s + 1 < nsteps) GSTAGE(cur ^ 1, (s + 1) * 64);
    __builtin_amdgcn_sched_barrier(0);
    const char* ab = lds + cur * 16384;
    const char* wb = lds + 32768 + cur * 16384;
    __builtin_amdgcn_s_setprio(1);
    #pragma unroll
    for (int s4 = 0; s4 < 4; ++s4) {
      const int off = (s4 * 32 + lh16) ^ swz;
      bf16x8 am0 = *(const bf16x8*)(ab + (qg * 64 + l31) * 128 + off);
      bf16x8 am1 = *(const bf16x8*)(ab + (qg * 64 + 32 + l31) * 128 + off);
      bf16x8 wn0 = *(const bf16x8*)(wb + (ng * 64 + l31) * 128 + off);
      bf16x8 wn1 = *(const bf16x8*)(wb + (ng * 64 + 32 + l31) * 128 + off);
      acc00 = __builtin_amdgcn_mfma_f32_32x32x16_bf16(wn0, am0, acc00, 0, 0, 0);
      acc01 = __builtin_amdgcn_mfma_f32_32x32x16_bf16(wn1, am0, acc01, 0, 0, 0);
      acc10 = __builtin_amdgcn_mfma_f32_32x32x16_bf16(wn0, am1, acc10, 0, 0, 0);
      acc11 = __builtin_amdgcn_mfma_f32_32x32x16_bf16(wn1, am1, acc11, 0, 0, 0);
    }
    __builtin_amdgcn_s_setprio(0);
    asm volatile("s_waitcnt vmcnt(0)" ::: "memory");
    sbar();
  }
#undef GSTAGE

  // epilogue: spill to LDS (XOR-swizzled cols), then coalesced store
  float* Ls = (float*)lds;
  {
    const int m0 = qg * 64 + l31;
    const int k0 = (m0 & 7) << 2;
    #pragma unroll
    for (int r = 0; r < 16; ++r) {
      const int nd = ng * 64 + (r & 3) + 8 * (r >> 2) + 4 * lh;
      Ls[m0 * 128 + (nd ^ k0)] = acc00[r];
      Ls[m0 * 128 + ((nd + 32) ^ k0)] = acc01[r];
      Ls[(m0 + 32) * 128 + (nd ^ k0)] = acc10[r];
      Ls[(m0 + 32) * 128 + ((nd + 32) ^ k0)] = acc11[r];
    }
  }
  sbar();
  #pragma unroll
  for (int p = 0; p < 16; ++p) {
    int idx = tid + 256 * p;
    int m = idx >> 5, c4 = (idx & 31) << 2;
    float4 v = *(const float4*)&Ls[m * 128 + (c4 ^ ((m & 7) << 2))];
    int col = colBase + c4;
    float4 bv = *(const float4*)&bias[col];
    v.x += bv.x; v.y += bv.y; v.z += bv.z; v.w += bv.w;
    if (ACT) {
      v.x = lrelu_f(v.x); v.y = lrelu_f(v.y);
      v.z = lrelu_f(v.z); v.w = lrelu_f(v.w);
    }
    size_t o = (size_t)(rowBase + m) * N + col;
    if (STOREF32) *(float4*)&C[o] = v;
    if (STOREBF) {
      ushort4 q;
      q.x = f2bf(v.x * bscale); q.y = f2bf(v.y * bscale);
      q.z = f2bf(v.z * bscale); q.w = f2bf(v.w * bscale);
      *(ushort4*)&Cb[o] = q;
    }
  }
}

// ---------------------------------------------------------------------------
// Dual GEMM, SHARED A: C1b = bf16(A@W1+b1), C2b = bf16(A@W2+b2). bf16 ONLY.
// ---------------------------------------------------------------------------
__global__ __launch_bounds__(256, 2)
void gemm_dualA(const u16* __restrict__ A, const u16* __restrict__ W1t,
                const u16* __restrict__ W2t,
                const float* __restrict__ b1, const float* __restrict__ b2,
                u16* __restrict__ C1b, u16* __restrict__ C2b) {
  __shared__ char lds[65536];   // A [0,16K) W1 [16K,32K) W2 [32K,48K); Ls 64K
  const int tid = threadIdx.x;
  const int w = tid >> 6, l = tid & 63;
  const int l31 = l & 31, lh = l >> 5, lh16 = lh << 4;
  const int qg = w & 1, ng = w >> 1;
  const int swz = (l31 & 7) << 4;
  const int rowBase = blockIdx.y * 128;
  const int colBase = blockIdx.x * 128;

  f32x16 z;
  #pragma unroll
  for (int i = 0; i < 16; i++) z[i] = 0.f;
  f32x16 p00 = z, p01 = z, p10 = z, p11 = z;
  f32x16 q00 = z, q01 = z, q10 = z, q11 = z;

  #pragma unroll 1
  for (int s = 0; s < 8; ++s) {
    {
      const int r_ = tid >> 3, j_ = tid & 7;
      const int js_ = ((j_ ^ (r_ & 7)) << 3);
      const u16* as_ = A + (size_t)rowBase * DIM + s * 64;
      const u16* w1_ = W1t + (size_t)colBase * DIM + s * 64;
      const u16* w2_ = W2t + (size_t)colBase * DIM + s * 64;
      #pragma unroll
      for (int p_ = 0; p_ < 4; ++p_) {
        __builtin_amdgcn_global_load_lds(
          (const __attribute__((address_space(1))) void*)(as_ + (size_t)(r_ + 32 * p_) * DIM + js_),
          (__attribute__((address_space(3))) void*)(lds + w * 1024 + p_ * 4096), 16, 0, 0);
        __builtin_amdgcn_global_load_lds(
          (const __attribute__((address_space(1))) void*)(w1_ + (size_t)(r_ + 32 * p_) * DIM + js_),
          (__attribute__((address_space(3))) void*)(lds + 16384 + w * 1024 + p_ * 4096), 16, 0, 0);
        __builtin_amdgcn_global_load_lds(
          (const __attribute__((address_space(1))) void*)(w2_ + (size_t)(r_ + 32 * p_) * DIM + js_),
          (__attribute__((address_space(3))) void*)(lds + 32768 + w * 1024 + p_ * 4096), 16, 0, 0);
      }
    }
    asm volatile("s_waitcnt vmcnt(0)" ::: "memory");
    sbar();
    const char* ab = lds;
    const char* w1b = lds + 16384;
    const char* w2b = lds + 32768;
    __builtin_amdgcn_s_setprio(1);
    #pragma unroll
    for (int s4 = 0; s4 < 4; ++s4) {
      const int off = (s4 * 32 + lh16) ^ swz;
      bf16x8 am0 = *(const bf16x8*)(ab + (qg * 64 + l31) * 128 + off);
      bf16x8 am1 = *(const bf16x8*)(ab + (qg * 64 + 32 + l31) * 128 + off);
      bf16x8 x0 = *(const bf16x8*)(w1b + (ng * 64 + l31) * 128 + off);
      bf16x8 x1 = *(const bf16x8*)(w1b + (ng * 64 + 32 + l31) * 128 + off);
      bf16x8 y0 = *(const bf16x8*)(w2b + (ng * 64 + l31) * 128 + off);
      bf16x8 y1 = *(const bf16x8*)(w2b + (ng * 64 + 32 + l31) * 128 + off);
      p00 = __builtin_amdgcn_mfma_f32_32x32x16_bf16(x0, am0, p00, 0, 0, 0);
      p01 = __builtin_amdgcn_mfma_f32_32x32x16_bf16(x1, am0, p01, 0, 0, 0);
      p10 = __builtin_amdgcn_mfma_f32_32x32x16_bf16(x0, am1, p10, 0, 0, 0);
      p11 = __builtin_amdgcn_mfma_f32_32x32x16_bf16(x1, am1, p11, 0, 0, 0);
      q00 = __builtin_amdgcn_mfma_f32_32x32x16_bf16(y0, am0, q00, 0, 0, 0);
      q01 = __builtin_amdgcn_mfma_f32_32x32x16_bf16(y1, am0, q01, 0, 0, 0);
      q10 = __builtin_amdgcn_mfma_f32_32x32x16_bf16(y0, am1, q10, 0, 0, 0);
      q11 = __builtin_amdgcn_mfma_f32_32x32x16_bf16(y1, am1, q11, 0, 0, 0);
    }
    __builtin_amdgcn_s_setprio(0);
    sbar();                                   // reads done before next stage
  }

  float* Ls = (float*)lds;
  const int m0 = qg * 64 + l31;
  const int k0 = (m0 & 7) << 2;
  // ---- pass 1: C1 (bf16) ----
  #pragma unroll
  for (int r = 0; r < 16; ++r) {
    const int nd = ng * 64 + (r & 3) + 8 * (r >> 2) + 4 * lh;
    Ls[m0 * 128 + (nd ^ k0)] = p00[r];
    Ls[m0 * 128 + ((nd + 32) ^ k0)] = p01[r];
    Ls[(m0 + 32) * 128 + (nd ^ k0)] = p10[r];
    Ls[(m0 + 32) * 128 + ((nd + 32) ^ k0)] = p11[r];
  }
  sbar();
  #pragma unroll
  for (int p = 0; p < 16; ++p) {
    int idx = tid + 256 * p;
    int m = idx >> 5, c4 = (idx & 31) << 2;
    float4 v = *(const float4*)&Ls[m * 128 + (c4 ^ ((m & 7) << 2))];
    int col = colBase + c4;
    float4 bv = *(const float4*)&b1[col];
    v.x += bv.x; v.y += bv.y; v.z += bv.z; v.w += bv.w;
    size_t o = (size_t)(rowBase + m) * DIM + col;
    ushort4 qo;
    qo.x = f2bf(v.x); qo.y = f2bf(v.y); qo.z = f2bf(v.z); qo.w = f2bf(v.w);
    *(ushort4*)&C1b[o] = qo;
  }
  sbar();
  // ---- pass 2: C2 (bf16) ----
  #pragma unroll
  for (int r = 0; r < 16; ++r) {
    const int nd = ng * 64 + (r & 3) + 8 * (r >> 2) + 4 * lh;
    Ls[m0 * 128 + (nd ^ k0)] = q00[r];
    Ls[m0 * 128 + ((nd + 32) ^ k0)] = q01[r];
    Ls[(m0 + 32) * 128 + (nd ^ k0)] = q10[r];
    Ls[(m0 + 32) * 128 + ((nd + 32) ^ k0)] = q11[r];
  }
  sbar();
  #pragma unroll
  for (int p = 0; p < 16; ++p) {
    int idx = tid + 256 * p;
    int m = idx >> 5, c4 = (idx & 31) << 2;
    float4 v = *(const float4*)&Ls[m * 128 + (c4 ^ ((m & 7) << 2))];
    int col = colBase + c4;
    float4 bv = *(const float4*)&b2[col];
    v.x += bv.x; v.y += bv.y; v.z += bv.z; v.w += bv.w;
    size_t o = (size_t)(rowBase + m) * DIM + col;
    ushort4 qo;
    qo.x = f2bf(v.x); qo.y = f2bf(v.y); qo.z = f2bf(v.z); qo.w = f2bf(v.w);
    *(ushort4*)&C2b[o] = qo;
  }
}

// ---------------------------------------------------------------------------
// Dual GEMM, SUMMED: Cb = bf16(lrelu(A1@W1+b1) + lrelu(A2@W2+b2)). bf16 only.
// ---------------------------------------------------------------------------
__global__ __launch_bounds__(256, 2)
void gemm_dualsum(const u16* __restrict__ A1, const u16* __restrict__ A2,
                  const u16* __restrict__ W1t, const u16* __restrict__ W2t,
                  const float* __restrict__ b1, const float* __restrict__ b2,
                  u16* __restrict__ Cb) {
  __shared__ char lds[65536];   // A1 0 | A2 16K | W1 32K | W2 48K; Ls 64K
  const int tid = threadIdx.x;
  const int w = tid >> 6, l = tid & 63;
  const int l31 = l & 31, lh = l >> 5, lh16 = lh << 4;
  const int qg = w & 1, ng = w >> 1;
  const int swz = (l31 & 7) << 4;
  const int rowBase = blockIdx.y * 128;
  const int colBase = blockIdx.x * 128;

  f32x16 z;
  #pragma unroll
  for (int i = 0; i < 16; i++) z[i] = 0.f;
  f32x16 p00 = z, p01 = z, p10 = z, p11 = z;
  f32x16 q00 = z, q01 = z, q10 = z, q11 = z;

  #pragma unroll 1
  for (int s = 0; s < 8; ++s) {
    {
      const int r_ = tid >> 3, j_ = tid & 7;
      const int js_ = ((j_ ^ (r_ & 7)) << 3);
      const u16* a1_ = A1 + (size_t)rowBase * DIM + s * 64;
      const u16* a2_ = A2 + (size_t)rowBase * DIM + s * 64;
      const u16* w1_ = W1t + (size_t)colBase * DIM + s * 64;
      const u16* w2_ = W2t + (size_t)colBase * DIM + s * 64;
      #pragma unroll
      for (int p_ = 0; p_ < 4; ++p_) {
        __builtin_amdgcn_global_load_lds(
          (const __attribute__((address_space(1))) void*)(a1_ + (size_t)(r_ + 32 * p_) * DIM + js_),
          (__attribute__((address_space(3))) void*)(lds + w * 1024 + p_ * 4096), 16, 0, 0);
        __builtin_amdgcn_global_load_lds(
          (const __attribute__((address_space(1))) void*)(a2_ + (size_t)(r_ + 32 * p_) * DIM + js_),
          (__attribute__((address_space(3))) void*)(lds + 16384 + w * 1024 + p_ * 4096), 16, 0, 0);
        __builtin_amdgcn_global_load_lds(
          (const __attribute__((address_space(1))) void*)(w1_ + (size_t)(r_ + 32 * p_) * DIM + js_),
          (__attribute__((address_space(3))) void*)(lds + 32768 + w * 1024 + p_ * 4096), 16, 0, 0);
        __builtin_amdgcn_global_load_lds(
          (const __attribute__((address_space(1))) void*)(w2_ + (size_t)(r_ + 32 * p_) * DIM + js_),
          (__attribute__((address_space(3))) void*)(lds + 49152 + w * 1024 + p_ * 4096), 16, 0, 0);
      }
    }
    asm volatile("s_waitcnt vmcnt(0)" ::: "memory");
    sbar();
    const char* a1b = lds;
    const char* a2b = lds + 16384;
    const char* w1b = lds + 32768;
    const char* w2b = lds + 49152;
    __builtin_amdgcn_s_setprio(1);
    #pragma unroll
    for (int s4 = 0; s4 < 4; ++s4) {
      const int off = (s4 * 32 + lh16) ^ swz;
      bf16x8 am0 = *(const bf16x8*)(a1b + (qg * 64 + l31) * 128 + off);
      bf16x8 am1 = *(const bf16x8*)(a1b + (qg * 64 + 32 + l31) * 128 + off);
      bf16x8 bm0 = *(const bf16x8*)(a2b + (qg * 64 + l31) * 128 + off);
      bf16x8 bm1 = *(const bf16x8*)(a2b + (qg * 64 + 32 + l31) * 128 + off);
      bf16x8 x0 = *(const bf16x8*)(w1b + (ng * 64 + l31) * 128 + off);
      bf16x8 x1 = *(const bf16x8*)(w1b + (ng * 64 + 32 + l31) * 128 + off);
      bf16x8 y0 = *(const bf16x8*)(w2b + (ng * 64 + l31) * 128 + off);
      bf16x8 y1 = *(const bf16x8*)(w2b + (ng * 64 + 32 + l31) * 128 + off);
      p00 = __builtin_amdgcn_mfma_f32_32x32x16_bf16(x0, am0, p00, 0, 0, 0);
      p01 = __builtin_amdgcn_mfma_f32_32x32x16_bf16(x1, am0, p01, 0, 0, 0);
      p10 = __builtin_amdgcn_mfma_f32_32x32x16_bf16(x0, am1, p10, 0, 0, 0);
      p11 = __builtin_amdgcn_mfma_f32_32x32x16_bf16(x1, am1, p11, 0, 0, 0);
      q00 = __builtin_amdgcn_mfma_f32_32x32x16_bf16(y0, bm0, q00, 0, 0, 0);
      q01 = __builtin_amdgcn_mfma_f32_32x32x16_bf16(y1, bm0, q01, 0, 0, 0);
      q10 = __builtin_amdgcn_mfma_f32_32x32x16_bf16(y0, bm1, q10, 0, 0, 0);
      q11 = __builtin_amdgcn_mfma_f32_32x32x16_bf16(y1, bm1, q11, 0, 0, 0);
    }
    __builtin_amdgcn_s_setprio(0);
    sbar();
  }

  // epilogue: combined value at spill (bias + lrelu + sum), then coalesced
  float* Ls = (float*)lds;
  const int m0 = qg * 64 + l31;
  const int k0 = (m0 & 7) << 2;
  #pragma unroll
  for (int r = 0; r < 16; ++r) {
    const int nd = ng * 64 + (r & 3) + 8 * (r >> 2) + 4 * lh;
    const int c0 = colBase + nd, c1 = colBase + nd + 32;
    Ls[m0 * 128 + (nd ^ k0)] =
        lrelu_f(p00[r] + b1[c0]) + lrelu_f(q00[r] + b2[c0]);
    Ls[m0 * 128 + ((nd + 32) ^ k0)] =
        lrelu_f(p01[r] + b1[c1]) + lrelu_f(q01[r] + b2[c1]);
    Ls[(m0 + 32) * 128 + (nd ^ k0)] =
        lrelu_f(p10[r] + b1[c0]) + lrelu_f(q10[r] + b2[c0]);
    Ls[(m0 + 32) * 128 + ((nd + 32) ^ k0)] =
        lrelu_f(p11[r] + b1[c1]) + lrelu_f(q11[r] + b2[c1]);
  }
  sbar();
  #pragma unroll
  for (int p = 0; p < 16; ++p) {
    int idx = tid + 256 * p;
    int m = idx >> 5, c4 = (idx & 31) << 2;
    float4 v = *(const float4*)&Ls[m * 128 + (c4 ^ ((m & 7) << 2))];
    int col = colBase + c4;
    size_t o = (size_t)(rowBase + m) * DIM + col;
    ushort4 qo;
    qo.x = f2bf(v.x); qo.y = f2bf(v.y); qo.z = f2bf(v.z); qo.w = f2bf(v.w);
    *(ushort4*)&Cb[o] = qo;
  }
}

// ---------------------------------------------------------------------------
// MFMA attn-logit + per-row top-6 — R9-verified pipeline. Inputs now UNSCALED
// bf16; selection on raw logits (monotone == same set), scale applied to the
// 6 outputs only.
// ---------------------------------------------------------------------------
#define T6(tv, tix, vv, cc) do { float v_ = (vv); \
  if (v_ > tv[5]) { tv[5] = v_; tix[5] = (cc); \
    if (tv[5] > tv[4]) { float t=tv[4];tv[4]=tv[5];tv[5]=t; int q=tix[4];tix[4]=tix[5];tix[5]=q; } \
    if (tv[4] > tv[3]) { float t=tv[3];tv[3]=tv[4];tv[4]=t; int q=tix[3];tix[3]=tix[4];tix[4]=q; } \
    if (tv[3] > tv[2]) { float t=tv[2];tv[2]=tv[3];tv[3]=t; int q=tix[2];tix[2]=tix[3];tix[3]=q; } \
    if (tv[2] > tv[1]) { float t=tv[1];tv[1]=tv[2];tv[2]=t; int q=tix[1];tix[1]=tix[2];tix[2]=q; } \
    if (tv[1] > tv[0]) { float t=tv[0];tv[0]=tv[1];tv[1]=t; int q=tix[0];tix[0]=tix[1];tix[1]=q; } \
  } } while (0)

__global__ __launch_bounds__(256, 2)
void attn_topk_mfma(const u16* __restrict__ EHb, const u16* __restrict__ ETb,
                    float* __restrict__ TWp, int* __restrict__ TIp) {
  __shared__ char lds[49152];            // 3 shared B buffers x 16 KB
  const int tid = threadIdx.x;
  const int w = tid >> 6, l = tid & 63;
  const int l31 = l & 31, lh = l >> 5;

  const int bid = blockIdx.x;
  const int xcd = bid & 7;
  const int split = xcd & 3;
  const int rowBase = ((xcd >> 2) * 64 + (bid >> 3)) * 128;
  const int qrow = rowBase + w * 32 + l31;     // this lane's query row

  bf16x8 areg[32];
  {
    const u16* ap = EHb + (size_t)qrow * DIM + lh * 8;
    #pragma unroll
    for (int ks = 0; ks < 32; ++ks)
      areg[ks] = *(const bf16x8*)(ap + ks * 16);
  }

  f32x16 z;
  #pragma unroll
  for (int i = 0; i < 16; i++) z[i] = 0.f;
  f32x16 acc0 = z, acc1 = z;

  float tv[KSEL]; int tix[KSEL];
  #pragma unroll
  for (int k = 0; k < KSEL; k++) { tv[k] = -INFINITY; tix[k] = 0x7fffffff; }

#define STAGE(bufi_, ph_) do { \
    const int ct_ = (ph_) >> 2, kc_ = (ph_) & 3; \
    char* db_ = lds + (bufi_) * 16384; \
    const u16* bs_ = ETb + (size_t)(split * COLS_PER_SPLIT + ct_ * 64) * DIM + kc_ * 128; \
    _Pragma("unroll") \
    for (int p_ = 0; p_ < 4; ++p_) { \
      const int c_ = (w * 4 + p_) * 64 + l; \
      const int rn_ = c_ >> 4; \
      const int js_ = ((c_ & 15) ^ (rn_ & 15)) << 3; \
      __builtin_amdgcn_global_load_lds( \
        (const __attribute__((address_space(1))) void*)(bs_ + (size_t)rn_ * DIM + js_), \
        (__attribute__((address_space(3))) void*)(db_ + (w * 4 + p_) * 1024), 16, 0, 0); \
    } \
  } while (0)

  int bufr = 0;
  STAGE(0, 0);
  STAGE(1, 1);
  asm volatile("s_waitcnt vmcnt(4)" ::: "memory");   // stage(0) landed

  #pragma unroll 1
  for (int ct = 0; ct < 64; ++ct) {
    #pragma unroll
    for (int kc = 0; kc < 4; ++kc) {
      sbar();                                  // stage(p) landed; p-1 reads done
      const char* db = lds + bufr * 16384;
      __builtin_amdgcn_s_setprio(1);
      #pragma unroll
      for (int s = 0; s < 8; ++s) {
        const int j0 = ((s * 2 + lh) ^ (l31 & 15)) * 16;
        bf16x8 bn0 = *(const bf16x8*)(db + l31 * 256 + j0);
        const int r1 = 32 + l31;
        const int j1 = ((s * 2 + lh) ^ (r1 & 15)) * 16;
        bf16x8 bn1 = *(const bf16x8*)(db + r1 * 256 + j1);
        acc0 = __builtin_amdgcn_mfma_f32_32x32x16_bf16(bn0, areg[kc * 8 + s], acc0, 0, 0, 0);
        acc1 = __builtin_amdgcn_mfma_f32_32x32x16_bf16(bn1, areg[kc * 8 + s], acc1, 0, 0, 0);
      }
      __builtin_amdgcn_s_setprio(0);
      if (kc == 3) {
        const int cb = split * COLS_PER_SPLIT + ct * 64 + 4 * lh;
        #pragma unroll
        for (int r = 0; r < 16; ++r) {
          const int nd = cb + (r & 3) + 8 * (r >> 2);
          T6(tv, tix, acc0[r], nd);
          T6(tv, tix, acc1[r], nd + 32);
        }
        acc0 = z; acc1 = z;
      }
      __builtin_amdgcn_sched_barrier(0);
      {
        const int p = ct * 4 + kc;
        if (p + 2 < 256) {
          const int bs = (bufr >= 1) ? bufr - 1 : bufr + 2;   // (bufr+2)%3
          STAGE(bs, p + 2);
        }
        if (p < 254) { asm volatile("s_waitcnt vmcnt(4)" ::: "memory"); }
        else         { asm volatile("s_waitcnt vmcnt(0)" ::: "memory"); }
      }
      bufr = (bufr == 2) ? 0 : bufr + 1;
    }
  }
#undef STAGE

  // merge the two lh-half lists for this q-row (partner lane = l ^ 32)
  {
    float pv[KSEL]; int pi[KSEL];
    #pragma unroll
    for (int k = 0; k < KSEL; k++) {
      pv[k] = __shfl_xor(tv[k], 32);
      pi[k] = __shfl_xor(tix[k], 32);
    }
    #pragma unroll
    for (int k = 0; k < KSEL; k++) {
      float cv = pv[k]; int ci = pi[k];
      if ((cv > tv[5]) || (cv == tv[5] && ci < tix[5])) {
        tv[5] = cv; tix[5] = ci;
        if ((tv[5] > tv[4]) || (tv[5] == tv[4] && tix[5] < tix[4])) {
          float t = tv[4]; tv[4] = tv[5]; tv[5] = t;
          int q = tix[4]; tix[4] = tix[5]; tix[5] = q; }
        if ((tv[4] > tv[3]) || (tv[4] == tv[3] && tix[4] < tix[3])) {
          float t = tv[3]; tv[3] = tv[4]; tv[4] = t;
          int q = tix[3]; tix[3] = tix[4]; tix[4] = q; }
        if ((tv[3] > tv[2]) || (tv[3] == tv[2] && tix[3] < tix[2])) {
          float t = tv[2]; tv[2] = tv[3]; tv[3] = t;
          int q = tix[2]; tix[2] = tix[3]; tix[3] = q; }
        if ((tv[2] > tv[1]) || (tv[2] == tv[1] && tix[2] < tix[1])) {
          float t = tv[1]; tv[1] = tv[2]; tv[2] = t;
          int q = tix[1]; tix[1] = tix[2]; tix[2] = q; }
        if ((tv[1] > tv[0]) || (tv[1] == tv[0] && tix[1] < tix[0])) {
          float t = tv[0]; tv[0] = tv[1]; tv[1] = t;
          int q = tix[0]; tix[0] = tix[1]; tix[1] = q; }
      }
    }
  }
  if (lh == 0) {
    size_t o = ((size_t)split * NROWS + qrow) * KSEL;
    #pragma unroll
    for (int k = 0; k < KSEL; k++) {
      TWp[o + k] = tv[k] * ATT_SCALE;          // scale applied post-selection
      TIp[o + k] = tix[k];
    }
  }
}

// ---------------------------------------------------------------------------
// Neighbor aggregation + inline 4-split top-6 merge. One wave per row.
// Reads bf16 e_h / e_t; writes bf16 s_in / b_in.
// ---------------------------------------------------------------------------
__global__ __launch_bounds__(256)
void neighbor_kernel(const u16* __restrict__ EHb, const u16* __restrict__ ETb,
                     const float* __restrict__ TWp, const int* __restrict__ TIp,
                     u16* __restrict__ SINb, u16* __restrict__ BINb) {
  const int lane = threadIdx.x & 63;
  const int row = blockIdx.x * 4 + (threadIdx.x >> 6);
  const u16* eh = EHb + (size_t)row * DIM;
  float ehv[8];
  #pragma unroll
  for (int u = 0; u < 8; u++) ehv[u] = bf2f(eh[u * 64 + lane]);

  float tw[KSEL]; int ti[KSEL];
  #pragma unroll
  for (int k = 0; k < KSEL; k++) { tw[k] = -INFINITY; ti[k] = 0x7fffffff; }
  #pragma unroll
  for (int s = 0; s < NSPLIT; s++) {
    size_t o = ((size_t)s * NROWS + row) * KSEL;
    #pragma unroll
    for (int k = 0; k < KSEL; k++) {
      float cv = TWp[o + k]; int ci = TIp[o + k];
      if ((cv > tw[5]) || (cv == tw[5] && ci < ti[5])) {
        tw[5] = cv; ti[5] = ci;
        if ((tw[5] > tw[4]) || (tw[5] == tw[4] && ti[5] < ti[4])) {
          float t = tw[4]; tw[4] = tw[5]; tw[5] = t;
          int q = ti[4]; ti[4] = ti[5]; ti[5] = q; }
        if ((tw[4] > tw[3]) || (tw[4] == tw[3] && ti[4] < ti[3])) {
          float t = tw[3]; tw[3] = tw[4]; tw[4] = t;
          int q = ti[3]; ti[3] = ti[4]; ti[4] = q; }
        if ((tw[3] > tw[2]) || (tw[3] == tw[2] && ti[3] < ti[2])) {
          float t = tw[2]; tw[2] = tw[3]; tw[3] = t;
          int q = ti[2]; ti[2] = ti[3]; ti[3] = q; }
        if ((tw[2] > tw[1]) || (tw[2] == tw[1] && ti[2] < ti[1])) {
          float t = tw[1]; tw[1] = tw[2]; tw[2] = t;
          int q = ti[1]; ti[1] = ti[2]; ti[2] = q; }
        if ((tw[1] > tw[0]) || (tw[1] == tw[0] && ti[1] < ti[0])) {
          float t = tw[0]; tw[0] = tw[1]; tw[1] = t;
          int q = ti[0]; ti[0] = ti[1]; ti[1] = q; }
      }
    }
  }

  float m = tw[0];
  #pragma unroll
  for (int k = 1; k < KSEL; k++) m = fmaxf(m, tw[k]);
  float p[KSEL], ps = 0.f;
  #pragma unroll
  for (int k = 0; k < KSEL; k++) { p[k] = expf(tw[k] - m); ps += p[k]; }
  float inv = 1.f / ps;
  #pragma unroll
  for (int k = 0; k < KSEL; k++) p[k] *= inv;

  float nb[KSEL][8];
  float kaw[KSEL];
  #pragma unroll
  for (int k = 0; k < KSEL; k++) {
    const u16* et = ETb + (size_t)ti[k] * DIM;
    float snb = 0.f, sg = 0.f;
    #pragma unroll
    for (int u = 0; u < 8; u++) {
      float nbv = bf2f(et[u * 64 + lane]);
      nb[k][u] = nbv;
      float ehr = p[k] * nbv + (1.f - p[k]) * ehv[u];
      float g = tanhf(ehv[u] + ehr);
      snb += nbv; sg += g;
    }
    #pragma unroll
    for (int off = 32; off > 0; off >>= 1) {
      snb += __shfl_xor(snb, off);
      sg  += __shfl_xor(sg, off);
    }
    kaw[k] = snb * sg;
  }
  float km = kaw[0];
  #pragma unroll
  for (int k = 1; k < KSEL; k++) km = fmaxf(km, kaw[k]);
  float kp[KSEL], ks = 0.f;
  #pragma unroll
  for (int k = 0; k < KSEL; k++) { kp[k] = expf(kaw[k] - km); ks += kp[k]; }
  float kinv = 1.f / ks;
  #pragma unroll
  for (int k = 0; k < KSEL; k++) kp[k] *= kinv;

  #pragma unroll
  for (int u = 0; u < 8; u++) {
    float enh = 0.f;
    #pragma unroll
    for (int k = 0; k < KSEL; k++) enh += kp[k] * nb[k][u];
    size_t o = (size_t)row * DIM + u * 64 + lane;
    SINb[o] = f2bf(ehv[u] + enh);
    BINb[o] = f2bf(ehv[u] * enh);
  }
}

// a[row] = dot(hidden_bf16[row][0:256], att2_w) + b  (one wave per row)
__global__ __launch_bounds__(256)
void att2_kernel(const u16* __restrict__ HIDb, const float* __restrict__ w2,
                 const float* __restrict__ b2, float* __restrict__ ASC) {
  const int lane = threadIdx.x & 63;
  const int row = blockIdx.x * 4 + (threadIdx.x >> 6);
  ushort4 hv = ((const ushort4*)(HIDb + (size_t)row * 256))[lane];
  float4 wv = ((const float4*)w2)[lane];
  float s = bf2f(hv.x) * wv.x + bf2f(hv.y) * wv.y +
            bf2f(hv.z) * wv.z + bf2f(hv.w) * wv.w;
  #pragma unroll
  for (int off = 32; off > 0; off >>= 1) s += __shfl_xor(s, off);
  if (lane == 0) ASC[row] = s + b2[0];
}

__global__ __launch_bounds__(1024)
void areduce(const float* __restrict__ ASC, float* __restrict__ stats) {
  __shared__ float sm[1024];
  int t = threadIdx.x;
  float m = -INFINITY;
  for (int i = t; i < NROWS; i += 1024) m = fmaxf(m, ASC[i]);
  sm[t] = m; __syncthreads();
  for (int s = 512; s > 0; s >>= 1) {
    if (t < s) sm[t] = fmaxf(sm[t], sm[t + s]);
    __syncthreads();
  }
  float mx = sm[0]; __syncthreads();
  float sum = 0.f;
  for (int i = t; i < NROWS; i += 1024) sum += expf(ASC[i] - mx);
  sm[t] = sum; __syncthreads();
  for (int s = 512; s > 0; s >>= 1) {
    if (t < s) sm[t] += sm[t + s];
    __syncthreads();
  }
  if (t == 0) { stats[0] = mx; stats[1] = sm[0]; }
}

__global__ __launch_bounds__(256)
void pooled_partial(const u16* __restrict__ EMBb, const float* __restrict__ ASC,
                    const float* __restrict__ stats, float* __restrict__ part) {
  int col = blockIdx.x * 64 + (threadIdx.x & 63);
  int sub = threadIdx.x >> 6;
  float mx = stats[0];
  int rEnd = blockIdx.y * 512 + 512;
  float s = 0.f;
  for (int r = blockIdx.y * 512 + sub; r < rEnd; r += 4)
    s += expf(ASC[r] - mx) * bf2f(EMBb[(size_t)r * DIM + col]);
  __shared__ float sh[4][64];
  sh[sub][threadIdx.x & 63] = s;
  __syncthreads();
  if (threadIdx.x < 64) {
    float tot = sh[0][threadIdx.x] + sh[1][threadIdx.x] +
                sh[2][threadIdx.x] + sh[3][threadIdx.x];
    part[(size_t)blockIdx.y * DIM + col] = tot;
  }
}

__global__ __launch_bounds__(512)
void final_kernel(const float* __restrict__ part, const float* __restrict__ stats,
                  const float* __restrict__ ln_g, const float* __restrict__ ln_b,
                  const float* __restrict__ fc_w, const float* __restrict__ fc_b,
                  float* __restrict__ out) {
  __shared__ float sh[512];
  int t = threadIdx.x;
  float s = 0.f;
  for (int j = 0; j < 32; j++) s += part[j * DIM + t];
  float pooled = s / stats[1];
  sh[t] = pooled; __syncthreads();
  for (int off = 256; off > 0; off >>= 1) {
    if (t < off) sh[t] += sh[t + off];
    __syncthreads();
  }
  float mu = sh[0] * (1.f / DIM); __syncthreads();
  float dv = pooled - mu;
  sh[t] = dv * dv; __syncthreads();
  for (int off = 256; off > 0; off >>= 1) {
    if (t < off) sh[t] += sh[t + off];
    __syncthreads();
  }
  float var = sh[0] * (1.f / DIM); __syncthreads();
  float normed = dv * rsqrtf(var + 1e-5f) * ln_g[t] + ln_b[t];
  sh[t] = normed * fc_w[t * 2 + 0]; __syncthreads();
  for (int off = 256; off > 0; off >>= 1) {
    if (t < off) sh[t] += sh[t + off];
    __syncthreads();
  }
  float l0 = sh[0] + fc_b[0]; __syncthreads();
  sh[t] = normed * fc_w[t * 2 + 1]; __syncthreads();
  for (int off = 256; off > 0; off >>= 1) {
    if (t < off) sh[t] += sh[t + off];
    __syncthreads();
  }
  float l1 = sh[0] + fc_b[1];
  if (t == 0) {
    float mm = fmaxf(l0, l1);
    float e0 = expf(l0 - mm), e1 = expf(l1 - mm);
    float si = 1.f / (e0 + e1);
    out[0] = l0; out[1] = l1; out[2] = e0 * si; out[3] = e1 * si;
  }
}

// ---------------------------------------------------------------------------
extern "C" void kernel_launch(void* const* d_in, const int* in_sizes, int n_in,
                              void* d_out, int out_size, void* d_ws, size_t ws_size,
                              hipStream_t stream) {
  (void)in_sizes; (void)n_in; (void)out_size; (void)ws_size;
  const float* x      = (const float*)d_in[0];
  const float* fc1_w  = (const float*)d_in[1];
  const float* fc1_b  = (const float*)d_in[2];
  const float* wh_w   = (const float*)d_in[3];
  const float* wh_b   = (const float*)d_in[4];
  const float* wt_w   = (const float*)d_in[5];
  const float* wt_b   = (const float*)d_in[6];
  const float* lin1_w = (const float*)d_in[7];
  const float* lin1_b = (const float*)d_in[8];
  const float* lin2_w = (const float*)d_in[9];
  const float* lin2_b = (const float*)d_in[10];
  const float* att1_w = (const float*)d_in[11];
  const float* att1_b = (const float*)d_in[12];
  const float* att2_w = (const float*)d_in[13];
  const float* att2_b = (const float*)d_in[14];
  const float* ln_g   = (const float*)d_in[15];
  const float* ln_b   = (const float*)d_in[16];
  const float* fc_w   = (const float*)d_in[17];
  const float* fc_b   = (const float*)d_in[18];
  float* out = (float*)d_out;

  char* ws = (char*)d_ws;
  float* B0   = (float*)(ws);                       // h0 f32
  u16*   sinb = (u16*)(ws + 33554432);              // [xb] -> s_in bf16
  u16*   binb = (u16*)(ws + 67108864);              // b_in bf16
  float* TWp  = (float*)(ws + 100663296);
  int*   TIp  = (int*)  (ws + 100663296 + 1572864);
  float* part = (float*)(ws + 100663296 + 3145728 + 786432);
  float* mean = (float*)(ws + 100663296 + 3145728 + 786432 + 65536);
  float* ascr = (float*)(ws + 100663296 + 3145728 + 786432 + 65536 + 2048);
  float* stats= (float*)(ws + 100663296 + 3145728 + 786432 + 65536 + 2048 + 65536);
  u16*   hb   = (u16*)(ws + 104732672);             // h bf16 -> embb
  u16*   EHb  = (u16*)(ws + 104732672 + 16777216);  // e_h bf16 -> HIDb
  u16*   ETb  = (u16*)(ws + 104732672 + 33554432);  // e_t bf16
  u16*   WT   = (u16*)(ws + 104732672 + 50331648);  // transposed bf16 weights
  u16* fc1t = WT;
  u16* wht  = fc1t + 196608;
  u16* wtt  = wht + 262144;
  u16* lin1t= wtt + 262144;
  u16* lin2t= lin1t + 262144;
  u16* att1t= lin2t + 262144;
  u16* xb   = sinb;          // temp: dead before neighbor writes sinb
  u16* embb = hb;            // emb bf16 overwrites h (dead after dualA)
  u16* HIDb = EHb;           // hidden bf16 overwrites e_h (dead after neighbor)

  // 0. all bf16 conversions in one launch
  prep<<<8448, 256, 0, stream>>>(x, xb, fc1_w, fc1t, wh_w, wht, wt_w, wtt,
                                 lin1_w, lin1t, lin2_w, lin2t, att1_w, att1t);
  // 1. h0 = lrelu(x @ fc1_w + b)  (f32 only; needed in colsum/h_fix)
  gemm_bf16<1,0,1><<<dim3(4,128), 256, 0, stream>>>(xb, fc1t, fc1_b, B0, nullptr, 1.f, 384, 512);
  // 2-4. column mean; hb = bf16((h0+mean)*0.5)
  colsum_partial<<<dim3(8,32), 256, 0, stream>>>(B0, part);
  finalize_mean<<<1, 512, 0, stream>>>(part, mean);
  h_fix_bf<<<4096, 256, 0, stream>>>(B0, mean, hb);
  // 5. e_h & e_t in ONE dual-GEMM: bf16 only, both UNSCALED
  gemm_dualA<<<dim3(4,128), 256, 0, stream>>>(hb, wht, wtt, wh_b, wt_b, EHb, ETb);
  // 6. fused MFMA attn-logit + top-6 per split (R9 pipeline; scale on output)
  attn_topk_mfma<<<512, 256, 0, stream>>>(EHb, ETb, TWp, TIp);
  // 7. neighbor aggregation (bf16 in, inline merge) -> bf16 s_in / b_in
  neighbor_kernel<<<4096, 256, 0, stream>>>(EHb, ETb, TWp, TIp, sinb, binb);
  // 8. emb = lrelu(sin@lin1+b1) + lrelu(bin@lin2+b2), bf16 only
  gemm_dualsum<<<dim3(4,128), 256, 0, stream>>>(sinb, binb, lin1t, lin2t,
                                                lin1_b, lin2_b, embb);
  // 9. hidden = lrelu(emb@att1+b) -> bf16 only
  gemm_bf16<1,1,0><<<dim3(2,128), 256, 0, stream>>>(embb, att1t, att1_b, nullptr, HIDb, 1.f, 512, 256);
  // 10-13. readout
  att2_kernel<<<4096, 256, 0, stream>>>(HIDb, att2_w, att2_b, ascr);
  areduce<<<1, 1024, 0, stream>>>(ascr, stats);
  pooled_partial<<<dim3(8,32), 256, 0, stream>>>(embb, ascr, stats, part);
  final_kernel<<<1, 512, 0, stream>>>(part, stats, ln_g, ln_b, fc_w, fc_b, out);
}